// Round 5
// baseline (953.666 us; speedup 1.0000x reference)
//
#include <hip/hip_runtime.h>

#define FCn 64      // FC
#define LDP 68      // padded LDS row stride (floats)
#define TEB 64      // edges per block (pass 1)
#define GJK 576     // 9*64 floats of G per node
#define ABP 12      // padded A-row stride per node
#define ZBLK 512    // zero-fill blocks appended to precomp grid

__device__ __forceinline__ float silu_f(float x) { return x / (1.f + __expf(-x)); }

// ---------------- precompute: fold s, rad_w2/rad_b2, proj_w*, 0.25 into
// MT (224x64, transposed: MT[c][k]), cvec(224), b0s(128).
// Blocks >= 65 zero-fill G/Ab and cnt (replaces two hipMemsetAsync).
__global__ __launch_bounds__(256) void precomp_kernel(
    const float* __restrict__ exp_w, const float* __restrict__ exp_b,
    const float* __restrict__ rad_w2, const float* __restrict__ rad_b2,
    const float* __restrict__ proj_w0, const float* __restrict__ proj_b0,
    const float* __restrict__ proj_w1, const float* __restrict__ proj_w2,
    float* __restrict__ MT, float* __restrict__ cvec, float* __restrict__ b0s,
    float* __restrict__ zbase, long long zf4, int* __restrict__ cnt, int Nn)
{
    if (blockIdx.x >= 65) {
        const long long tid = (long long)(blockIdx.x - 65) * 256 + threadIdx.x;
        const long long stride = (long long)ZBLK * 256;
        float4 z = make_float4(0.f, 0.f, 0.f, 0.f);
        for (long long i = tid; i < zf4; i += stride) ((float4*)zbase)[i] = z;
        for (long long i = tid; i < Nn; i += stride) cnt[i] = 0;
        return;
    }
    const int r = blockIdx.x;   // 0..63 -> M row r; 64 -> cvec/b0s
    const int c = threadIdx.x;  // 0..255
    const float* wrow = (r < FCn) ? (rad_w2 + (long long)r * 384) : rad_b2;
    float acc = 0.f;
    if (c < 128) {
        for (int q = 0; q < 128; ++q)
            acc += wrow[q] * (exp_w[q] + exp_b[q]) * proj_w0[q * 128 + c];
    } else if (c < 192) {
        const int d = c - 128;
        for (int q = 0; q < 128; ++q)
            acc += wrow[128 + q] * (exp_w[q] + exp_b[q]) * proj_w1[q * 64 + d];
    } else if (c < 224) {
        const int d = c - 192;
        for (int q = 0; q < 128; ++q)
            acc += wrow[256 + q] * (exp_w[q] + exp_b[q]) * proj_w2[q * 32 + d];
    }
    acc *= 0.25f;  // 1/sqrt(AVG_AGG)
    if (r < FCn) {
        if (c < 224) MT[c * FCn + r] = acc;   // MT[c][k]
    } else {
        cvec[c] = acc;
        if (c < 128) b0s[c] = 0.25f * proj_b0[c];
    }
}

// ---------------- CSR build
__global__ __launch_bounds__(256) void hist_kernel(const int* __restrict__ dst, int* __restrict__ cnt, int E)
{
    for (int e = blockIdx.x * 256 + threadIdx.x; e < E; e += gridDim.x * 256)
        atomicAdd(&cnt[dst[e]], 1);
}

__global__ __launch_bounds__(256) void scan_kernel(const int* __restrict__ cnt, int* __restrict__ off,
                                                   int* __restrict__ cur, int Nn, int Etot)
{
    __shared__ int part[256];
    __shared__ int spart[257];
    const int t = threadIdx.x;
    const int per = (Nn + 255) / 256;
    int s = 0;
    #pragma unroll 8
    for (int i = 0; i < per; ++i) {
        const int idx = t * per + i;
        if (idx < Nn) s += cnt[idx];
    }
    part[t] = s;
    __syncthreads();
    if (t == 0) {
        int run = 0;
        spart[0] = 0;
        for (int i = 0; i < 256; ++i) { run += part[i]; spart[i + 1] = run; }
    }
    __syncthreads();
    int run = spart[t];
    #pragma unroll 8
    for (int i = 0; i < per; ++i) {
        const int idx = t * per + i;
        if (idx < Nn) { off[idx] = run; cur[idx] = run; run += cnt[idx]; }
    }
    if (t == 0) off[Nn] = Etot;
}

__global__ __launch_bounds__(256) void scatter_kernel(const int* __restrict__ dst, int* __restrict__ cur,
                                                      int* __restrict__ eids, int E)
{
    for (int e = blockIdx.x * 256 + threadIdx.x; e < E; e += gridDim.x * 256) {
        const int pos = atomicAdd(&cur[dst[e]], 1);
        eids[pos] = e;
    }
}

// ---------------- pass 1: GEMM1 + in-register LN/silu + segment-accumulate G
__global__ __launch_bounds__(256, 7) void accumG_kernel(
    const float* __restrict__ edge_attr,    // E x 9
    const float* __restrict__ edge_scalars, // E x 64
    const int*   __restrict__ eids,         // E (sorted pos -> edge id)
    const int*   __restrict__ edge_dst,     // E
    const float* __restrict__ rad_w1,       // 64 x 64
    const float* __restrict__ rad_b1,       // 64
    const float* __restrict__ rad_gamma,    // 64
    const float* __restrict__ rad_beta,     // 64
    float* __restrict__ G,                  // N x 576 (zero-initialized)
    float* __restrict__ Ab,                 // N x 12  (zero-initialized)
    int E)
{
    __shared__ float XT[FCn * LDP];   // X^T [k][e]; reused as He [e][k] after LN
    __shared__ float Ea[TEB * ABP];   // [e][j]
    __shared__ int   dst_l[TEB];
    const int t = threadIdx.x;
    const int p0 = blockIdx.x * TEB;

    if (t < TEB) {
        const int p = p0 + t;
        const int eid = (p < E) ? eids[p] : -1;
        dst_l[t] = (eid >= 0) ? edge_dst[eid] : -1;
    }

    // ---- stage X^T (gathered 256B rows) + edge_attr (eids read via L1 broadcast)
    #pragma unroll
    for (int i = 0; i < 4; ++i) {
        const int idx = i * 256 + t;
        const int e  = idx >> 4;
        const int kq = idx & 15;
        const int p  = p0 + e;
        const int eid = (p < E) ? eids[p] : -1;
        float4 v = make_float4(0.f, 0.f, 0.f, 0.f);
        if (eid >= 0) v = *(const float4*)(edge_scalars + (long long)eid * FCn + kq * 4);
        XT[(kq * 4 + 0) * LDP + e] = v.x;
        XT[(kq * 4 + 1) * LDP + e] = v.y;
        XT[(kq * 4 + 2) * LDP + e] = v.z;
        XT[(kq * 4 + 3) * LDP + e] = v.w;
    }
    for (int i = t; i < TEB * 9; i += 256) {
        const int e = i / 9, j = i - e * 9;
        const int p = p0 + e;
        const int eid = (p < E) ? eids[p] : -1;
        Ea[e * ABP + j] = (eid >= 0) ? edge_attr[(long long)eid * 9 + j] : 0.f;
    }
    __syncthreads();

    // ---- GEMM1: H = X @ W1 + b1 (64e x 64c), per-thread 4x4, acc in regs
    const int eg = t >> 4, cg = t & 15;
    float a[4][4];
    #pragma unroll
    for (int i = 0; i < 4; ++i)
        #pragma unroll
        for (int j = 0; j < 4; ++j) a[i][j] = 0.f;
    for (int k = 0; k < FCn; ++k) {
        const float4 xv = *(const float4*)&XT[k * LDP + eg * 4];
        const float4 wv = *(const float4*)&rad_w1[k * FCn + cg * 4];
        const float xe[4] = {xv.x, xv.y, xv.z, xv.w};
        const float wc[4] = {wv.x, wv.y, wv.z, wv.w};
        #pragma unroll
        for (int i = 0; i < 4; ++i)
            #pragma unroll
            for (int j = 0; j < 4; ++j)
                a[i][j] += xe[i] * wc[j];
    }
    {
        const float4 bv = *(const float4*)&rad_b1[cg * 4];
        const float bb[4] = {bv.x, bv.y, bv.z, bv.w};
        #pragma unroll
        for (int i = 0; i < 4; ++i)
            #pragma unroll
            for (int j = 0; j < 4; ++j) a[i][j] += bb[j];
    }

    // ---- LN stats: reduce across the 16 cg-lanes (contiguous in wave)
    float s1[4], s2[4];
    #pragma unroll
    for (int i = 0; i < 4; ++i) {
        s1[i] = a[i][0] + a[i][1] + a[i][2] + a[i][3];
        s2[i] = a[i][0]*a[i][0] + a[i][1]*a[i][1] + a[i][2]*a[i][2] + a[i][3]*a[i][3];
    }
    #pragma unroll
    for (int m = 1; m < 16; m <<= 1) {
        #pragma unroll
        for (int i = 0; i < 4; ++i) {
            s1[i] += __shfl_xor(s1[i], m);
            s2[i] += __shfl_xor(s2[i], m);
        }
    }

    __syncthreads();   // all XT (X^T) reads done; safe to overwrite with He

    {
        const float4 gm = *(const float4*)&rad_gamma[cg * 4];
        const float4 bt = *(const float4*)&rad_beta[cg * 4];
        const float gv[4] = {gm.x, gm.y, gm.z, gm.w};
        const float bv2[4] = {bt.x, bt.y, bt.z, bt.w};
        #pragma unroll
        for (int i = 0; i < 4; ++i) {
            const float mu  = s1[i] * (1.f / 64.f);
            const float var = s2[i] * (1.f / 64.f) - mu * mu;
            const float rs  = rsqrtf(var + 1e-5f);
            float o[4];
            #pragma unroll
            for (int j = 0; j < 4; ++j) {
                const float x = (a[i][j] - mu) * rs * gv[j] + bv2[j];
                o[j] = silu_f(x);
            }
            *(float4*)&XT[(eg * 4 + i) * LDP + cg * 4] = make_float4(o[0], o[1], o[2], o[3]);
        }
    }
    __syncthreads();

    // ---- segment accumulation of G and A (registers), flush on dst change.
    // dst_l is non-decreasing (CSR order) -> wave-uniform 4-edge fast path.
    const int k  = t & 63;
    const int jg = t >> 6;            // 0..3
    const int j0 = jg, j1 = jg + 4;   // jg==0 additionally owns j=8
    const bool has2 = (jg == 0);
    float g0 = 0.f, g1 = 0.f, g2 = 0.f;
    float a0 = 0.f, a1 = 0.f, a2 = 0.f;
    int curn = dst_l[0];
    int e = 0;
    while (e < TEB) {
        const int nid = dst_l[e];
        if (nid != curn) {
            if (curn >= 0) {
                float* gp = G + (long long)curn * GJK;
                atomicAdd(gp + j0 * 64 + k, g0);
                atomicAdd(gp + j1 * 64 + k, g1);
                if (has2) atomicAdd(gp + 8 * 64 + k, g2);
                if (k == 0) {
                    float* ap = Ab + (long long)curn * ABP;
                    atomicAdd(ap + j0, a0);
                    atomicAdd(ap + j1, a1);
                    if (has2) atomicAdd(ap + 8, a2);
                }
            }
            g0 = g1 = g2 = 0.f; a0 = a1 = a2 = 0.f;
            curn = nid;
        }
        if (nid < 0) break;
        if (e + 4 <= TEB && dst_l[e + 3] == nid) {
            #pragma unroll
            for (int u = 0; u < 4; ++u) {
                const int eu = e + u;
                const float h  = XT[eu * LDP + k];
                const float e0 = Ea[eu * ABP + j0];
                const float e1 = Ea[eu * ABP + j1];
                g0 = fmaf(e0, h, g0); a0 += e0;
                g1 = fmaf(e1, h, g1); a1 += e1;
                if (has2) {
                    const float e2 = Ea[eu * ABP + 8];
                    g2 = fmaf(e2, h, g2); a2 += e2;
                }
            }
            e += 4;
        } else {
            const float h  = XT[e * LDP + k];
            const float e0 = Ea[e * ABP + j0];
            const float e1 = Ea[e * ABP + j1];
            g0 = fmaf(e0, h, g0); a0 += e0;
            g1 = fmaf(e1, h, g1); a1 += e1;
            if (has2) {
                const float e2 = Ea[e * ABP + 8];
                g2 = fmaf(e2, h, g2); a2 += e2;
            }
            e += 1;
        }
    }
    if (curn >= 0) {
        float* gp = G + (long long)curn * GJK;
        atomicAdd(gp + j0 * 64 + k, g0);
        atomicAdd(gp + j1 * 64 + k, g1);
        if (has2) atomicAdd(gp + 8 * 64 + k, g2);
        if (k == 0) {
            float* ap = Ab + (long long)curn * ABP;
            atomicAdd(ap + j0, a0);
            atomicAdd(ap + j1, a1);
            if (has2) atomicAdd(ap + 8, a2);
        }
    }
}

// ---------------- pass 2: out[n,c] = G[n,j(c),:]·MT[t(c),:] + Ab[n,j(c)]*cvec[t(c)]
//                                     + (c<128 ? deg*b0s[c] : 0)
// __launch_bounds__(512, 1): 256-VGPR cap. (512,4) capped at 64 VGPRs and the
// default heuristic capped at 128 — both spilled m[16]+acc[8] (1.3-2.8 GB of
// scratch traffic, VALUBusy 3-5%). Live set ~100 regs needs the full cap.
// No LDS: G rows are read with wave-broadcast addresses (same jIdx -> same
// row), served from L1 after first touch. One 8-node chunk per block.
__global__ __launch_bounds__(512, 1) void project_kernel(
    const float* __restrict__ G, const float* __restrict__ Ab,
    const int*   __restrict__ off,
    const float* __restrict__ MT, const float* __restrict__ cvec,
    const float* __restrict__ b0s,
    float* __restrict__ out, int Nn)
{
    const int t = threadIdx.x;

    // out col t -> (T col, edge_attr col)
    int tIdx = 0, jIdx = 0;
    if (t < 128)      { tIdx = t; jIdx = 0; }
    else if (t < 320) { const int idx = t - 128; tIdx = 128 + idx / 3; jIdx = 1 + idx % 3; }
    else if (t < 480) { const int idx = t - 320; tIdx = 192 + idx / 5; jIdx = 4 + idx % 5; }

    // MT row into registers (64 floats); constants from global (L2-resident)
    float4 m[16];
    {
        const float* mrow = MT + tIdx * FCn;
        #pragma unroll
        for (int q = 0; q < 16; ++q) m[q] = *(const float4*)(mrow + q * 4);
    }
    const float cvv = cvec[tIdx];
    const float bsv = (t < 128) ? b0s[t] : 0.f;

    const int n0 = blockIdx.x * 8;
    if (n0 >= Nn) return;

    float acc[8];
    #pragma unroll
    for (int nb = 0; nb < 8; ++nb) {
        const int n = min(n0 + nb, Nn - 1);
        const int deg = off[n + 1] - off[n];
        acc[nb] = Ab[(long long)n * ABP + jIdx] * cvv + (float)deg * bsv;
    }
    #pragma unroll
    for (int q = 0; q < 16; ++q) {
        const float4 mq = m[q];
        #pragma unroll
        for (int nb = 0; nb < 8; ++nb) {
            const int n = min(n0 + nb, Nn - 1);
            const float4 g = *(const float4*)(G + (long long)n * GJK + jIdx * 64 + q * 4);
            acc[nb] += mq.x * g.x + mq.y * g.y + mq.z * g.z + mq.w * g.w;
        }
    }
    if (t < 480) {
        #pragma unroll
        for (int nb = 0; nb < 8; ++nb)
            if (n0 + nb < Nn)
                out[(long long)(n0 + nb) * 480 + t] = acc[nb];
    }
}

extern "C" void kernel_launch(void* const* d_in, const int* in_sizes, int n_in,
                              void* d_out, int out_size, void* d_ws, size_t ws_size,
                              hipStream_t stream)
{
    const float* edge_attr    = (const float*)d_in[1];
    const float* edge_scalars = (const float*)d_in[2];
    const int*   edge_dst     = (const int*)d_in[4];
    const float* exp_w     = (const float*)d_in[6];
    const float* exp_b     = (const float*)d_in[7];
    const float* rad_w1    = (const float*)d_in[8];
    const float* rad_b1    = (const float*)d_in[9];
    const float* rad_gamma = (const float*)d_in[10];
    const float* rad_beta  = (const float*)d_in[11];
    const float* rad_w2    = (const float*)d_in[12];
    const float* rad_b2    = (const float*)d_in[13];
    const float* proj_w0   = (const float*)d_in[14];
    const float* proj_b0   = (const float*)d_in[15];
    const float* proj_w1   = (const float*)d_in[16];
    const float* proj_w2   = (const float*)d_in[17];
    float* out = (float*)d_out;
    const int E = in_sizes[4];
    const int Nn = out_size / 480;

    // ws layout: MT, cvec, b0s, off, cnt, cur, eids, G, Ab
    float* MT   = (float*)d_ws;                 // 224*64
    float* cvec = MT + 224 * FCn;               // 256
    float* b0s  = cvec + 256;                   // 128
    int* off  = (int*)(b0s + 128);              // Nn+1
    int* cnt  = off + (Nn + 1);                 // Nn
    int* cur  = cnt + Nn;                       // Nn
    int* eids = cur + Nn;                       // E
    size_t gOff = (size_t)((char*)(eids + E) - (char*)d_ws);
    gOff = (gOff + 255) & ~(size_t)255;
    float* G  = (float*)((char*)d_ws + gOff);   // Nn x 576
    float* Ab = G + (size_t)Nn * GJK;           // Nn x 12 (contiguous with G)

    const long long zf4 = ((long long)Nn * (GJK + ABP)) >> 2;  // G+Ab float4 count
    precomp_kernel<<<65 + ZBLK, 256, 0, stream>>>(exp_w, exp_b, rad_w2, rad_b2,
                                                  proj_w0, proj_b0, proj_w1, proj_w2,
                                                  MT, cvec, b0s, G, zf4, cnt, Nn);
    hist_kernel<<<512, 256, 0, stream>>>(edge_dst, cnt, E);
    scan_kernel<<<1, 256, 0, stream>>>(cnt, off, cur, Nn, E);
    scatter_kernel<<<512, 256, 0, stream>>>(edge_dst, cur, eids, E);

    const int blocks = (E + TEB - 1) / TEB;
    accumG_kernel<<<blocks, 256, 0, stream>>>(edge_attr, edge_scalars, eids, edge_dst,
                                              rad_w1, rad_b1, rad_gamma, rad_beta,
                                              G, Ab, E);
    const int pblocks = (Nn + 7) / 8;
    project_kernel<<<pblocks, 512, 0, stream>>>(G, Ab, off, MT, cvec, b0s, out, Nn);
}

// Round 6
// 622.774 us; speedup vs baseline: 1.5313x; 1.5313x over previous
//
#include <hip/hip_runtime.h>

#define FCn 64      // FC
#define LDP 68      // padded LDS row stride (floats)
#define TEB 64      // edges per block (pass 1)
#define GJK 576     // 9*64 floats of G per node
#define ABP 12      // padded A-row stride per node
#define ZBLK 512    // zero-fill blocks appended to precomp grid

__device__ __forceinline__ float silu_f(float x) { return x / (1.f + __expf(-x)); }

// ---------------- precompute: fold s, rad_w2/rad_b2, proj_w*, 0.25 into
// MT (224x64, transposed: MT[c][k]), cvec(224), b0s(128).
// Blocks >= 65 zero-fill G/Ab and cnt (replaces two hipMemsetAsync).
__global__ __launch_bounds__(256) void precomp_kernel(
    const float* __restrict__ exp_w, const float* __restrict__ exp_b,
    const float* __restrict__ rad_w2, const float* __restrict__ rad_b2,
    const float* __restrict__ proj_w0, const float* __restrict__ proj_b0,
    const float* __restrict__ proj_w1, const float* __restrict__ proj_w2,
    float* __restrict__ MT, float* __restrict__ cvec, float* __restrict__ b0s,
    float* __restrict__ zbase, long long zf4, int* __restrict__ cnt, int Nn)
{
    if (blockIdx.x >= 65) {
        const long long tid = (long long)(blockIdx.x - 65) * 256 + threadIdx.x;
        const long long stride = (long long)ZBLK * 256;
        float4 z = make_float4(0.f, 0.f, 0.f, 0.f);
        for (long long i = tid; i < zf4; i += stride) ((float4*)zbase)[i] = z;
        for (long long i = tid; i < Nn; i += stride) cnt[i] = 0;
        return;
    }
    const int r = blockIdx.x;   // 0..63 -> M row r; 64 -> cvec/b0s
    const int c = threadIdx.x;  // 0..255
    const float* wrow = (r < FCn) ? (rad_w2 + (long long)r * 384) : rad_b2;
    float acc = 0.f;
    if (c < 128) {
        for (int q = 0; q < 128; ++q)
            acc += wrow[q] * (exp_w[q] + exp_b[q]) * proj_w0[q * 128 + c];
    } else if (c < 192) {
        const int d = c - 128;
        for (int q = 0; q < 128; ++q)
            acc += wrow[128 + q] * (exp_w[q] + exp_b[q]) * proj_w1[q * 64 + d];
    } else if (c < 224) {
        const int d = c - 192;
        for (int q = 0; q < 128; ++q)
            acc += wrow[256 + q] * (exp_w[q] + exp_b[q]) * proj_w2[q * 32 + d];
    }
    acc *= 0.25f;  // 1/sqrt(AVG_AGG)
    if (r < FCn) {
        if (c < 224) MT[c * FCn + r] = acc;   // MT[c][k]
    } else {
        cvec[c] = acc;
        if (c < 128) b0s[c] = 0.25f * proj_b0[c];
    }
}

// ---------------- CSR build
__global__ __launch_bounds__(256) void hist_kernel(const int* __restrict__ dst, int* __restrict__ cnt, int E)
{
    for (int e = blockIdx.x * 256 + threadIdx.x; e < E; e += gridDim.x * 256)
        atomicAdd(&cnt[dst[e]], 1);
}

__global__ __launch_bounds__(256) void scan_kernel(const int* __restrict__ cnt, int* __restrict__ off,
                                                   int* __restrict__ cur, int Nn, int Etot)
{
    __shared__ int part[256];
    __shared__ int spart[257];
    const int t = threadIdx.x;
    const int per = (Nn + 255) / 256;
    int s = 0;
    #pragma unroll 8
    for (int i = 0; i < per; ++i) {
        const int idx = t * per + i;
        if (idx < Nn) s += cnt[idx];
    }
    part[t] = s;
    __syncthreads();
    if (t == 0) {
        int run = 0;
        spart[0] = 0;
        for (int i = 0; i < 256; ++i) { run += part[i]; spart[i + 1] = run; }
    }
    __syncthreads();
    int run = spart[t];
    #pragma unroll 8
    for (int i = 0; i < per; ++i) {
        const int idx = t * per + i;
        if (idx < Nn) { off[idx] = run; cur[idx] = run; run += cnt[idx]; }
    }
    if (t == 0) off[Nn] = Etot;
}

__global__ __launch_bounds__(256) void scatter_kernel(const int* __restrict__ dst, int* __restrict__ cur,
                                                      int* __restrict__ eids, int E)
{
    for (int e = blockIdx.x * 256 + threadIdx.x; e < E; e += gridDim.x * 256) {
        const int pos = atomicAdd(&cur[dst[e]], 1);
        eids[pos] = e;
    }
}

// ---------------- pass 1: GEMM1 + in-register LN/silu + segment-accumulate G
__global__ __launch_bounds__(256, 7) void accumG_kernel(
    const float* __restrict__ edge_attr,    // E x 9
    const float* __restrict__ edge_scalars, // E x 64
    const int*   __restrict__ eids,         // E (sorted pos -> edge id)
    const int*   __restrict__ edge_dst,     // E
    const float* __restrict__ rad_w1,       // 64 x 64
    const float* __restrict__ rad_b1,       // 64
    const float* __restrict__ rad_gamma,    // 64
    const float* __restrict__ rad_beta,     // 64
    float* __restrict__ G,                  // N x 576 (zero-initialized)
    float* __restrict__ Ab,                 // N x 12  (zero-initialized)
    int E)
{
    __shared__ float XT[FCn * LDP];   // X^T [k][e]; reused as He [e][k] after LN
    __shared__ float Ea[TEB * ABP];   // [e][j]
    __shared__ int   dst_l[TEB];
    const int t = threadIdx.x;
    const int p0 = blockIdx.x * TEB;

    if (t < TEB) {
        const int p = p0 + t;
        const int eid = (p < E) ? eids[p] : -1;
        dst_l[t] = (eid >= 0) ? edge_dst[eid] : -1;
    }

    // ---- stage X^T (gathered 256B rows) + edge_attr (eids read via L1 broadcast)
    #pragma unroll
    for (int i = 0; i < 4; ++i) {
        const int idx = i * 256 + t;
        const int e  = idx >> 4;
        const int kq = idx & 15;
        const int p  = p0 + e;
        const int eid = (p < E) ? eids[p] : -1;
        float4 v = make_float4(0.f, 0.f, 0.f, 0.f);
        if (eid >= 0) v = *(const float4*)(edge_scalars + (long long)eid * FCn + kq * 4);
        XT[(kq * 4 + 0) * LDP + e] = v.x;
        XT[(kq * 4 + 1) * LDP + e] = v.y;
        XT[(kq * 4 + 2) * LDP + e] = v.z;
        XT[(kq * 4 + 3) * LDP + e] = v.w;
    }
    for (int i = t; i < TEB * 9; i += 256) {
        const int e = i / 9, j = i - e * 9;
        const int p = p0 + e;
        const int eid = (p < E) ? eids[p] : -1;
        Ea[e * ABP + j] = (eid >= 0) ? edge_attr[(long long)eid * 9 + j] : 0.f;
    }
    __syncthreads();

    // ---- GEMM1: H = X @ W1 + b1 (64e x 64c), per-thread 4x4, acc in regs
    const int eg = t >> 4, cg = t & 15;
    float a[4][4];
    #pragma unroll
    for (int i = 0; i < 4; ++i)
        #pragma unroll
        for (int j = 0; j < 4; ++j) a[i][j] = 0.f;
    for (int k = 0; k < FCn; ++k) {
        const float4 xv = *(const float4*)&XT[k * LDP + eg * 4];
        const float4 wv = *(const float4*)&rad_w1[k * FCn + cg * 4];
        const float xe[4] = {xv.x, xv.y, xv.z, xv.w};
        const float wc[4] = {wv.x, wv.y, wv.z, wv.w};
        #pragma unroll
        for (int i = 0; i < 4; ++i)
            #pragma unroll
            for (int j = 0; j < 4; ++j)
                a[i][j] += xe[i] * wc[j];
    }
    {
        const float4 bv = *(const float4*)&rad_b1[cg * 4];
        const float bb[4] = {bv.x, bv.y, bv.z, bv.w};
        #pragma unroll
        for (int i = 0; i < 4; ++i)
            #pragma unroll
            for (int j = 0; j < 4; ++j) a[i][j] += bb[j];
    }

    // ---- LN stats: reduce across the 16 cg-lanes (contiguous in wave)
    float s1[4], s2[4];
    #pragma unroll
    for (int i = 0; i < 4; ++i) {
        s1[i] = a[i][0] + a[i][1] + a[i][2] + a[i][3];
        s2[i] = a[i][0]*a[i][0] + a[i][1]*a[i][1] + a[i][2]*a[i][2] + a[i][3]*a[i][3];
    }
    #pragma unroll
    for (int m = 1; m < 16; m <<= 1) {
        #pragma unroll
        for (int i = 0; i < 4; ++i) {
            s1[i] += __shfl_xor(s1[i], m);
            s2[i] += __shfl_xor(s2[i], m);
        }
    }

    __syncthreads();   // all XT (X^T) reads done; safe to overwrite with He

    {
        const float4 gm = *(const float4*)&rad_gamma[cg * 4];
        const float4 bt = *(const float4*)&rad_beta[cg * 4];
        const float gv[4] = {gm.x, gm.y, gm.z, gm.w};
        const float bv2[4] = {bt.x, bt.y, bt.z, bt.w};
        #pragma unroll
        for (int i = 0; i < 4; ++i) {
            const float mu  = s1[i] * (1.f / 64.f);
            const float var = s2[i] * (1.f / 64.f) - mu * mu;
            const float rs  = rsqrtf(var + 1e-5f);
            float o[4];
            #pragma unroll
            for (int j = 0; j < 4; ++j) {
                const float x = (a[i][j] - mu) * rs * gv[j] + bv2[j];
                o[j] = silu_f(x);
            }
            *(float4*)&XT[(eg * 4 + i) * LDP + cg * 4] = make_float4(o[0], o[1], o[2], o[3]);
        }
    }
    __syncthreads();

    // ---- segment accumulation of G and A (registers), flush on dst change.
    // dst_l is non-decreasing (CSR order) -> wave-uniform 4-edge fast path.
    const int k  = t & 63;
    const int jg = t >> 6;            // 0..3
    const int j0 = jg, j1 = jg + 4;   // jg==0 additionally owns j=8
    const bool has2 = (jg == 0);
    float g0 = 0.f, g1 = 0.f, g2 = 0.f;
    float a0 = 0.f, a1 = 0.f, a2 = 0.f;
    int curn = dst_l[0];
    int e = 0;
    while (e < TEB) {
        const int nid = dst_l[e];
        if (nid != curn) {
            if (curn >= 0) {
                float* gp = G + (long long)curn * GJK;
                atomicAdd(gp + j0 * 64 + k, g0);
                atomicAdd(gp + j1 * 64 + k, g1);
                if (has2) atomicAdd(gp + 8 * 64 + k, g2);
                if (k == 0) {
                    float* ap = Ab + (long long)curn * ABP;
                    atomicAdd(ap + j0, a0);
                    atomicAdd(ap + j1, a1);
                    if (has2) atomicAdd(ap + 8, a2);
                }
            }
            g0 = g1 = g2 = 0.f; a0 = a1 = a2 = 0.f;
            curn = nid;
        }
        if (nid < 0) break;
        if (e + 4 <= TEB && dst_l[e + 3] == nid) {
            #pragma unroll
            for (int u = 0; u < 4; ++u) {
                const int eu = e + u;
                const float h  = XT[eu * LDP + k];
                const float e0 = Ea[eu * ABP + j0];
                const float e1 = Ea[eu * ABP + j1];
                g0 = fmaf(e0, h, g0); a0 += e0;
                g1 = fmaf(e1, h, g1); a1 += e1;
                if (has2) {
                    const float e2 = Ea[eu * ABP + 8];
                    g2 = fmaf(e2, h, g2); a2 += e2;
                }
            }
            e += 4;
        } else {
            const float h  = XT[e * LDP + k];
            const float e0 = Ea[e * ABP + j0];
            const float e1 = Ea[e * ABP + j1];
            g0 = fmaf(e0, h, g0); a0 += e0;
            g1 = fmaf(e1, h, g1); a1 += e1;
            if (has2) {
                const float e2 = Ea[e * ABP + 8];
                g2 = fmaf(e2, h, g2); a2 += e2;
            }
            e += 1;
        }
    }
    if (curn >= 0) {
        float* gp = G + (long long)curn * GJK;
        atomicAdd(gp + j0 * 64 + k, g0);
        atomicAdd(gp + j1 * 64 + k, g1);
        if (has2) atomicAdd(gp + 8 * 64 + k, g2);
        if (k == 0) {
            float* ap = Ab + (long long)curn * ABP;
            atomicAdd(ap + j0, a0);
            atomicAdd(ap + j1, a1);
            if (has2) atomicAdd(ap + 8, a2);
        }
    }
}

// ---------------- pass 2: out[n,c] = G[n,j(c),:]·MT[t(c),:] + Ab[n,j(c)]*cvec[t(c)]
//                                     + (c<128 ? deg*b0s[c] : 0)
// REGISTER BUDGET IS THE DESIGN CONSTRAINT: the backend pins 512-thread
// kernels at <=128 VGPRs (measured 64/128/128 across three launch-bound
// settings; anything over spills to scratch -> 1.3-2.8 GB phantom traffic).
// m[16] (64 regs) + FOUR nodes at a time (acc[4] + 4 bases + in-flight
// loads ~= 100 regs total) fits under 128. Two sequential 4-node groups
// (#pragma unroll 1 prevents re-fusing) keep MT reuse at 8 nodes/thread.
// No LDS: G rows are wave-broadcast reads, 9 KB/group -> L1-resident.
__global__ __launch_bounds__(512) void project_kernel(
    const float* __restrict__ G, const float* __restrict__ Ab,
    const int*   __restrict__ off,
    const float* __restrict__ MT, const float* __restrict__ cvec,
    const float* __restrict__ b0s,
    float* __restrict__ out, int Nn)
{
    const int t = threadIdx.x;

    // out col t -> (T col, edge_attr col)
    int tIdx = 0, jIdx = 0;
    if (t < 128)      { tIdx = t; jIdx = 0; }
    else if (t < 320) { const int idx = t - 128; tIdx = 128 + idx / 3; jIdx = 1 + idx % 3; }
    else if (t < 480) { const int idx = t - 320; tIdx = 192 + idx / 5; jIdx = 4 + idx % 5; }

    // MT row into registers (64 floats); constants from global (L2-resident)
    float4 m[16];
    {
        const float* mrow = MT + tIdx * FCn;
        #pragma unroll
        for (int q = 0; q < 16; ++q) m[q] = *(const float4*)(mrow + q * 4);
    }
    const float cvv = cvec[tIdx];
    const float bsv = (t < 128) ? b0s[t] : 0.f;

    const int nbase = blockIdx.x * 8;

    #pragma unroll 1
    for (int g = 0; g < 2; ++g) {
        const int n0 = nbase + g * 4;
        if (n0 >= Nn) break;

        const float* gp[4];
        float acc[4];
        #pragma unroll
        for (int nb = 0; nb < 4; ++nb) {
            const int n = min(n0 + nb, Nn - 1);
            const int deg = off[n + 1] - off[n];
            acc[nb] = Ab[(long long)n * ABP + jIdx] * cvv + (float)deg * bsv;
            gp[nb] = G + (long long)n * GJK + jIdx * 64;
        }
        #pragma unroll
        for (int q = 0; q < 16; ++q) {
            const float4 mq = m[q];
            #pragma unroll
            for (int nb = 0; nb < 4; ++nb) {
                const float4 gv = *(const float4*)(gp[nb] + q * 4);
                acc[nb] += mq.x * gv.x + mq.y * gv.y + mq.z * gv.z + mq.w * gv.w;
            }
        }
        if (t < 480) {
            #pragma unroll
            for (int nb = 0; nb < 4; ++nb)
                if (n0 + nb < Nn)
                    out[(long long)(n0 + nb) * 480 + t] = acc[nb];
        }
    }
}

extern "C" void kernel_launch(void* const* d_in, const int* in_sizes, int n_in,
                              void* d_out, int out_size, void* d_ws, size_t ws_size,
                              hipStream_t stream)
{
    const float* edge_attr    = (const float*)d_in[1];
    const float* edge_scalars = (const float*)d_in[2];
    const int*   edge_dst     = (const int*)d_in[4];
    const float* exp_w     = (const float*)d_in[6];
    const float* exp_b     = (const float*)d_in[7];
    const float* rad_w1    = (const float*)d_in[8];
    const float* rad_b1    = (const float*)d_in[9];
    const float* rad_gamma = (const float*)d_in[10];
    const float* rad_beta  = (const float*)d_in[11];
    const float* rad_w2    = (const float*)d_in[12];
    const float* rad_b2    = (const float*)d_in[13];
    const float* proj_w0   = (const float*)d_in[14];
    const float* proj_b0   = (const float*)d_in[15];
    const float* proj_w1   = (const float*)d_in[16];
    const float* proj_w2   = (const float*)d_in[17];
    float* out = (float*)d_out;
    const int E = in_sizes[4];
    const int Nn = out_size / 480;

    // ws layout: MT, cvec, b0s, off, cnt, cur, eids, G, Ab
    float* MT   = (float*)d_ws;                 // 224*64
    float* cvec = MT + 224 * FCn;               // 256
    float* b0s  = cvec + 256;                   // 128
    int* off  = (int*)(b0s + 128);              // Nn+1
    int* cnt  = off + (Nn + 1);                 // Nn
    int* cur  = cnt + Nn;                       // Nn
    int* eids = cur + Nn;                       // E
    size_t gOff = (size_t)((char*)(eids + E) - (char*)d_ws);
    gOff = (gOff + 255) & ~(size_t)255;
    float* G  = (float*)((char*)d_ws + gOff);   // Nn x 576
    float* Ab = G + (size_t)Nn * GJK;           // Nn x 12 (contiguous with G)

    const long long zf4 = ((long long)Nn * (GJK + ABP)) >> 2;  // G+Ab float4 count
    precomp_kernel<<<65 + ZBLK, 256, 0, stream>>>(exp_w, exp_b, rad_w2, rad_b2,
                                                  proj_w0, proj_b0, proj_w1, proj_w2,
                                                  MT, cvec, b0s, G, zf4, cnt, Nn);
    hist_kernel<<<512, 256, 0, stream>>>(edge_dst, cnt, E);
    scan_kernel<<<1, 256, 0, stream>>>(cnt, off, cur, Nn, E);
    scatter_kernel<<<512, 256, 0, stream>>>(edge_dst, cur, eids, E);

    const int blocks = (E + TEB - 1) / TEB;
    accumG_kernel<<<blocks, 256, 0, stream>>>(edge_attr, edge_scalars, eids, edge_dst,
                                              rad_w1, rad_b1, rad_gamma, rad_beta,
                                              G, Ab, E);
    const int pblocks = (Nn + 7) / 8;
    project_kernel<<<pblocks, 512, 0, stream>>>(G, Ab, off, MT, cvec, b0s, out, Nn);
}

// Round 7
// 465.997 us; speedup vs baseline: 2.0465x; 1.3364x over previous
//
#include <hip/hip_runtime.h>

#define FCn 64      // FC
#define LDP 68      // padded LDS row stride (floats)
#define TEB 64      // edges per block (pass 1)
#define GJK 576     // 9*64 floats of G per node
#define GJS 612     // 9*68 padded LDS stride per node (project)
#define ABP 12      // padded A-row stride per node
#define ZBLK 512    // zero-fill blocks appended to precomp grid

__device__ __forceinline__ float silu_f(float x) { return x / (1.f + __expf(-x)); }

// ---------------- precompute: fold s, rad_w2/rad_b2, proj_w*, 0.25 into
// MT (224x64, transposed: MT[c][k]), cvec(224), b0s(128).
// Blocks >= 65 zero-fill G/Ab and cnt (replaces two hipMemsetAsync).
__global__ __launch_bounds__(256) void precomp_kernel(
    const float* __restrict__ exp_w, const float* __restrict__ exp_b,
    const float* __restrict__ rad_w2, const float* __restrict__ rad_b2,
    const float* __restrict__ proj_w0, const float* __restrict__ proj_b0,
    const float* __restrict__ proj_w1, const float* __restrict__ proj_w2,
    float* __restrict__ MT, float* __restrict__ cvec, float* __restrict__ b0s,
    float* __restrict__ zbase, long long zf4, int* __restrict__ cnt, int Nn)
{
    if (blockIdx.x >= 65) {
        const long long tid = (long long)(blockIdx.x - 65) * 256 + threadIdx.x;
        const long long stride = (long long)ZBLK * 256;
        float4 z = make_float4(0.f, 0.f, 0.f, 0.f);
        for (long long i = tid; i < zf4; i += stride) ((float4*)zbase)[i] = z;
        for (long long i = tid; i < Nn; i += stride) cnt[i] = 0;
        return;
    }
    const int r = blockIdx.x;   // 0..63 -> M row r; 64 -> cvec/b0s
    const int c = threadIdx.x;  // 0..255
    const float* wrow = (r < FCn) ? (rad_w2 + (long long)r * 384) : rad_b2;
    float acc = 0.f;
    if (c < 128) {
        for (int q = 0; q < 128; ++q)
            acc += wrow[q] * (exp_w[q] + exp_b[q]) * proj_w0[q * 128 + c];
    } else if (c < 192) {
        const int d = c - 128;
        for (int q = 0; q < 128; ++q)
            acc += wrow[128 + q] * (exp_w[q] + exp_b[q]) * proj_w1[q * 64 + d];
    } else if (c < 224) {
        const int d = c - 192;
        for (int q = 0; q < 128; ++q)
            acc += wrow[256 + q] * (exp_w[q] + exp_b[q]) * proj_w2[q * 32 + d];
    }
    acc *= 0.25f;  // 1/sqrt(AVG_AGG)
    if (r < FCn) {
        if (c < 224) MT[c * FCn + r] = acc;   // MT[c][k]
    } else {
        cvec[c] = acc;
        if (c < 128) b0s[c] = 0.25f * proj_b0[c];
    }
}

// ---------------- CSR build
__global__ __launch_bounds__(256) void hist_kernel(const int* __restrict__ dst, int* __restrict__ cnt, int E)
{
    for (int e = blockIdx.x * 256 + threadIdx.x; e < E; e += gridDim.x * 256)
        atomicAdd(&cnt[dst[e]], 1);
}

__global__ __launch_bounds__(256) void scan_kernel(const int* __restrict__ cnt, int* __restrict__ off,
                                                   int* __restrict__ cur, int Nn, int Etot)
{
    __shared__ int part[256];
    __shared__ int spart[257];
    const int t = threadIdx.x;
    const int per = (Nn + 255) / 256;
    int s = 0;
    #pragma unroll 8
    for (int i = 0; i < per; ++i) {
        const int idx = t * per + i;
        if (idx < Nn) s += cnt[idx];
    }
    part[t] = s;
    __syncthreads();
    if (t == 0) {
        int run = 0;
        spart[0] = 0;
        for (int i = 0; i < 256; ++i) { run += part[i]; spart[i + 1] = run; }
    }
    __syncthreads();
    int run = spart[t];
    #pragma unroll 8
    for (int i = 0; i < per; ++i) {
        const int idx = t * per + i;
        if (idx < Nn) { off[idx] = run; cur[idx] = run; run += cnt[idx]; }
    }
    if (t == 0) off[Nn] = Etot;
}

__global__ __launch_bounds__(256) void scatter_kernel(const int* __restrict__ dst, int* __restrict__ cur,
                                                      int* __restrict__ eids, int E)
{
    for (int e = blockIdx.x * 256 + threadIdx.x; e < E; e += gridDim.x * 256) {
        const int pos = atomicAdd(&cur[dst[e]], 1);
        eids[pos] = e;
    }
}

// ---------------- pass 1: GEMM1 + in-register LN/silu + segment-accumulate G
__global__ __launch_bounds__(256, 7) void accumG_kernel(
    const float* __restrict__ edge_attr,    // E x 9
    const float* __restrict__ edge_scalars, // E x 64
    const int*   __restrict__ eids,         // E (sorted pos -> edge id)
    const int*   __restrict__ edge_dst,     // E
    const float* __restrict__ rad_w1,       // 64 x 64
    const float* __restrict__ rad_b1,       // 64
    const float* __restrict__ rad_gamma,    // 64
    const float* __restrict__ rad_beta,     // 64
    float* __restrict__ G,                  // N x 576 (zero-initialized)
    float* __restrict__ Ab,                 // N x 12  (zero-initialized)
    int E)
{
    __shared__ float XT[FCn * LDP];   // X^T [k][e]; reused as He [e][k] after LN
    __shared__ float Ea[TEB * ABP];   // [e][j]
    __shared__ int   dst_l[TEB];
    const int t = threadIdx.x;
    const int p0 = blockIdx.x * TEB;

    if (t < TEB) {
        const int p = p0 + t;
        const int eid = (p < E) ? eids[p] : -1;
        dst_l[t] = (eid >= 0) ? edge_dst[eid] : -1;
    }

    // ---- stage X^T (gathered 256B rows) + edge_attr (eids read via L1 broadcast)
    #pragma unroll
    for (int i = 0; i < 4; ++i) {
        const int idx = i * 256 + t;
        const int e  = idx >> 4;
        const int kq = idx & 15;
        const int p  = p0 + e;
        const int eid = (p < E) ? eids[p] : -1;
        float4 v = make_float4(0.f, 0.f, 0.f, 0.f);
        if (eid >= 0) v = *(const float4*)(edge_scalars + (long long)eid * FCn + kq * 4);
        XT[(kq * 4 + 0) * LDP + e] = v.x;
        XT[(kq * 4 + 1) * LDP + e] = v.y;
        XT[(kq * 4 + 2) * LDP + e] = v.z;
        XT[(kq * 4 + 3) * LDP + e] = v.w;
    }
    for (int i = t; i < TEB * 9; i += 256) {
        const int e = i / 9, j = i - e * 9;
        const int p = p0 + e;
        const int eid = (p < E) ? eids[p] : -1;
        Ea[e * ABP + j] = (eid >= 0) ? edge_attr[(long long)eid * 9 + j] : 0.f;
    }
    __syncthreads();

    // ---- GEMM1: H = X @ W1 + b1 (64e x 64c), per-thread 4x4, acc in regs
    const int eg = t >> 4, cg = t & 15;
    float a[4][4];
    #pragma unroll
    for (int i = 0; i < 4; ++i)
        #pragma unroll
        for (int j = 0; j < 4; ++j) a[i][j] = 0.f;
    for (int k = 0; k < FCn; ++k) {
        const float4 xv = *(const float4*)&XT[k * LDP + eg * 4];
        const float4 wv = *(const float4*)&rad_w1[k * FCn + cg * 4];
        const float xe[4] = {xv.x, xv.y, xv.z, xv.w};
        const float wc[4] = {wv.x, wv.y, wv.z, wv.w};
        #pragma unroll
        for (int i = 0; i < 4; ++i)
            #pragma unroll
            for (int j = 0; j < 4; ++j)
                a[i][j] += xe[i] * wc[j];
    }
    {
        const float4 bv = *(const float4*)&rad_b1[cg * 4];
        const float bb[4] = {bv.x, bv.y, bv.z, bv.w};
        #pragma unroll
        for (int i = 0; i < 4; ++i)
            #pragma unroll
            for (int j = 0; j < 4; ++j) a[i][j] += bb[j];
    }

    // ---- LN stats: reduce across the 16 cg-lanes (contiguous in wave)
    float s1[4], s2[4];
    #pragma unroll
    for (int i = 0; i < 4; ++i) {
        s1[i] = a[i][0] + a[i][1] + a[i][2] + a[i][3];
        s2[i] = a[i][0]*a[i][0] + a[i][1]*a[i][1] + a[i][2]*a[i][2] + a[i][3]*a[i][3];
    }
    #pragma unroll
    for (int m = 1; m < 16; m <<= 1) {
        #pragma unroll
        for (int i = 0; i < 4; ++i) {
            s1[i] += __shfl_xor(s1[i], m);
            s2[i] += __shfl_xor(s2[i], m);
        }
    }

    __syncthreads();   // all XT (X^T) reads done; safe to overwrite with He

    {
        const float4 gm = *(const float4*)&rad_gamma[cg * 4];
        const float4 bt = *(const float4*)&rad_beta[cg * 4];
        const float gv[4] = {gm.x, gm.y, gm.z, gm.w};
        const float bv2[4] = {bt.x, bt.y, bt.z, bt.w};
        #pragma unroll
        for (int i = 0; i < 4; ++i) {
            const float mu  = s1[i] * (1.f / 64.f);
            const float var = s2[i] * (1.f / 64.f) - mu * mu;
            const float rs  = rsqrtf(var + 1e-5f);
            float o[4];
            #pragma unroll
            for (int j = 0; j < 4; ++j) {
                const float x = (a[i][j] - mu) * rs * gv[j] + bv2[j];
                o[j] = silu_f(x);
            }
            *(float4*)&XT[(eg * 4 + i) * LDP + cg * 4] = make_float4(o[0], o[1], o[2], o[3]);
        }
    }
    __syncthreads();

    // ---- segment accumulation of G and A (registers), flush on dst change.
    // dst_l is non-decreasing (CSR order) -> wave-uniform 4-edge fast path.
    const int k  = t & 63;
    const int jg = t >> 6;            // 0..3
    const int j0 = jg, j1 = jg + 4;   // jg==0 additionally owns j=8
    const bool has2 = (jg == 0);
    float g0 = 0.f, g1 = 0.f, g2 = 0.f;
    float a0 = 0.f, a1 = 0.f, a2 = 0.f;
    int curn = dst_l[0];
    int e = 0;
    while (e < TEB) {
        const int nid = dst_l[e];
        if (nid != curn) {
            if (curn >= 0) {
                float* gp = G + (long long)curn * GJK;
                atomicAdd(gp + j0 * 64 + k, g0);
                atomicAdd(gp + j1 * 64 + k, g1);
                if (has2) atomicAdd(gp + 8 * 64 + k, g2);
                if (k == 0) {
                    float* ap = Ab + (long long)curn * ABP;
                    atomicAdd(ap + j0, a0);
                    atomicAdd(ap + j1, a1);
                    if (has2) atomicAdd(ap + 8, a2);
                }
            }
            g0 = g1 = g2 = 0.f; a0 = a1 = a2 = 0.f;
            curn = nid;
        }
        if (nid < 0) break;
        if (e + 4 <= TEB && dst_l[e + 3] == nid) {
            #pragma unroll
            for (int u = 0; u < 4; ++u) {
                const int eu = e + u;
                const float h  = XT[eu * LDP + k];
                const float e0 = Ea[eu * ABP + j0];
                const float e1 = Ea[eu * ABP + j1];
                g0 = fmaf(e0, h, g0); a0 += e0;
                g1 = fmaf(e1, h, g1); a1 += e1;
                if (has2) {
                    const float e2 = Ea[eu * ABP + 8];
                    g2 = fmaf(e2, h, g2); a2 += e2;
                }
            }
            e += 4;
        } else {
            const float h  = XT[e * LDP + k];
            const float e0 = Ea[e * ABP + j0];
            const float e1 = Ea[e * ABP + j1];
            g0 = fmaf(e0, h, g0); a0 += e0;
            g1 = fmaf(e1, h, g1); a1 += e1;
            if (has2) {
                const float e2 = Ea[e * ABP + 8];
                g2 = fmaf(e2, h, g2); a2 += e2;
            }
            e += 1;
        }
    }
    if (curn >= 0) {
        float* gp = G + (long long)curn * GJK;
        atomicAdd(gp + j0 * 64 + k, g0);
        atomicAdd(gp + j1 * 64 + k, g1);
        if (has2) atomicAdd(gp + 8 * 64 + k, g2);
        if (k == 0) {
            float* ap = Ab + (long long)curn * ABP;
            atomicAdd(ap + j0, a0);
            atomicAdd(ap + j1, a1);
            if (has2) atomicAdd(ap + 8, a2);
        }
    }
}

// ---------------- pass 2: out[n,c] = G[n,j(c),:]·MT[t(c),:] + Ab[n,j(c)]*cvec[t(c)]
//                                     + (c<128 ? deg*b0s[c] : 0)
// Round-6 lesson: with G read directly from global, the compute loop's
// wave-broadcast loads (16 B per wave-instr, ~200-900 cy latency) left the
// kernel 95% stalled (VALUBusy 13%, HBM 4%). Split into phases:
//   (1) coalesced float4 streaming of the block's 8 G-rows into LDS
//       (9 independent loads/thread -> latency amortized),
//   (2) compute with m[16] in regs + LDS broadcast reads (padded 68-float
//       j-stride -> mixed-j waves hit disjoint bank quads; same-address
//       reads broadcast for free).
// Register budget (hard 128-VGPR cap for 512-thr blocks, measured r4-r6):
// m[16]=64 + acc[4] + staging temps ~= 100. acc[8] spills (r4) — keep two
// sequential 4-node groups (#pragma unroll 1).
__global__ __launch_bounds__(512) void project_kernel(
    const float* __restrict__ G, const float* __restrict__ Ab,
    const int*   __restrict__ off,
    const float* __restrict__ MT, const float* __restrict__ cvec,
    const float* __restrict__ b0s,
    float* __restrict__ out, int Nn)
{
    __shared__ float Gs[8 * GJS];     // 19584 B, [nb][j][68]
    const int t = threadIdx.x;

    // out col t -> (T col, edge_attr col)
    int tIdx = 0, jIdx = 0;
    if (t < 128)      { tIdx = t; jIdx = 0; }
    else if (t < 320) { const int idx = t - 128; tIdx = 128 + idx / 3; jIdx = 1 + idx % 3; }
    else if (t < 480) { const int idx = t - 320; tIdx = 192 + idx / 5; jIdx = 4 + idx % 5; }

    const int n0b = blockIdx.x * 8;

    // ---- phase 1: stage 8 nodes of G into LDS (coalesced float4 reads)
    for (int i = t; i < 8 * 144; i += 512) {
        const int nb  = i / 144;
        const int rem = i - nb * 144;           // float4 index within node row
        const int n   = n0b + nb;
        float4 v = make_float4(0.f, 0.f, 0.f, 0.f);
        if (n < Nn) v = *(const float4*)(G + (long long)n * GJK + rem * 4);
        *(float4*)(&Gs[nb * GJS + (rem >> 4) * 68 + (rem & 15) * 4]) = v;
    }

    // MT row into registers (64 floats); constants from global (L2-resident)
    float4 m[16];
    {
        const float* mrow = MT + tIdx * FCn;
        #pragma unroll
        for (int q = 0; q < 16; ++q) m[q] = *(const float4*)(mrow + q * 4);
    }
    const float cvv = cvec[tIdx];
    const float bsv = (t < 128) ? b0s[t] : 0.f;
    __syncthreads();

    // ---- phase 2: two sequential 4-node groups
    #pragma unroll 1
    for (int g = 0; g < 2; ++g) {
        const int n0 = n0b + g * 4;
        if (n0 >= Nn) break;

        float acc[4];
        #pragma unroll
        for (int nb = 0; nb < 4; ++nb) {
            const int n = min(n0 + nb, Nn - 1);
            const int deg = off[n + 1] - off[n];
            acc[nb] = Ab[(long long)n * ABP + jIdx] * cvv + (float)deg * bsv;
        }
        const float* gb = &Gs[(g * 4) * GJS + jIdx * 68];
        #pragma unroll
        for (int q = 0; q < 16; ++q) {
            const float4 mq = m[q];
            #pragma unroll
            for (int nb = 0; nb < 4; ++nb) {
                const float4 gv = *(const float4*)(gb + nb * GJS + q * 4);
                acc[nb] += mq.x * gv.x + mq.y * gv.y + mq.z * gv.z + mq.w * gv.w;
            }
        }
        if (t < 480) {
            #pragma unroll
            for (int nb = 0; nb < 4; ++nb)
                if (n0 + nb < Nn)
                    out[(long long)(n0 + nb) * 480 + t] = acc[nb];
        }
    }
}

extern "C" void kernel_launch(void* const* d_in, const int* in_sizes, int n_in,
                              void* d_out, int out_size, void* d_ws, size_t ws_size,
                              hipStream_t stream)
{
    const float* edge_attr    = (const float*)d_in[1];
    const float* edge_scalars = (const float*)d_in[2];
    const int*   edge_dst     = (const int*)d_in[4];
    const float* exp_w     = (const float*)d_in[6];
    const float* exp_b     = (const float*)d_in[7];
    const float* rad_w1    = (const float*)d_in[8];
    const float* rad_b1    = (const float*)d_in[9];
    const float* rad_gamma = (const float*)d_in[10];
    const float* rad_beta  = (const float*)d_in[11];
    const float* rad_w2    = (const float*)d_in[12];
    const float* rad_b2    = (const float*)d_in[13];
    const float* proj_w0   = (const float*)d_in[14];
    const float* proj_b0   = (const float*)d_in[15];
    const float* proj_w1   = (const float*)d_in[16];
    const float* proj_w2   = (const float*)d_in[17];
    float* out = (float*)d_out;
    const int E = in_sizes[4];
    const int Nn = out_size / 480;

    // ws layout: MT, cvec, b0s, off, cnt, cur, eids, G, Ab
    float* MT   = (float*)d_ws;                 // 224*64
    float* cvec = MT + 224 * FCn;               // 256
    float* b0s  = cvec + 256;                   // 128
    int* off  = (int*)(b0s + 128);              // Nn+1
    int* cnt  = off + (Nn + 1);                 // Nn
    int* cur  = cnt + Nn;                       // Nn
    int* eids = cur + Nn;                       // E
    size_t gOff = (size_t)((char*)(eids + E) - (char*)d_ws);
    gOff = (gOff + 255) & ~(size_t)255;
    float* G  = (float*)((char*)d_ws + gOff);   // Nn x 576
    float* Ab = G + (size_t)Nn * GJK;           // Nn x 12 (contiguous with G)

    const long long zf4 = ((long long)Nn * (GJK + ABP)) >> 2;  // G+Ab float4 count
    precomp_kernel<<<65 + ZBLK, 256, 0, stream>>>(exp_w, exp_b, rad_w2, rad_b2,
                                                  proj_w0, proj_b0, proj_w1, proj_w2,
                                                  MT, cvec, b0s, G, zf4, cnt, Nn);
    hist_kernel<<<512, 256, 0, stream>>>(edge_dst, cnt, E);
    scan_kernel<<<1, 256, 0, stream>>>(cnt, off, cur, Nn, E);
    scatter_kernel<<<512, 256, 0, stream>>>(edge_dst, cur, eids, E);

    const int blocks = (E + TEB - 1) / TEB;
    accumG_kernel<<<blocks, 256, 0, stream>>>(edge_attr, edge_scalars, eids, edge_dst,
                                              rad_w1, rad_b1, rad_gamma, rad_beta,
                                              G, Ab, E);
    const int pblocks = (Nn + 7) / 8;
    project_kernel<<<pblocks, 512, 0, stream>>>(G, Ab, off, MT, cvec, b0s, out, Nn);
}

// Round 9
// 464.093 us; speedup vs baseline: 2.0549x; 1.0041x over previous
//
#include <hip/hip_runtime.h>

#define FCn 64      // FC
#define TEB 64      // edges per block (pass 1)
#define GJK 576     // 9*64 floats of G per node
#define GJS 612     // 9*68 padded LDS stride per node (project)
#define ABP 12      // padded A-row stride per node (global Ab)
#define ZBLK 512    // zero-fill blocks appended to precomp grid
#define XSZ (64*68) // XT buffer: 64 rows x 68 stride, XOR swizzle stays in-row

__device__ __forceinline__ float silu_f(float x) { return x / (1.f + __expf(-x)); }
// In-row XOR swizzle: element [r][c] at r*68 + (c ^ (((r>>3)&7)<<2)).
// XOR value < 64 -> bijective within the row (r8's row-base shift overlapped
// rows 31/32 -> absmax 2.29). Staging-write banks: 2 lanes/bank (free);
// segment reads: permutation of 0..63 -> 2 lanes/bank; float4 ops stay
// aligned (XOR touches bits 2-4 only, float4 spans bits 0-1).
__device__ __forceinline__ int xidx(int r, int c) {
    return r * 68 + (c ^ (((r >> 3) & 7) << 2));
}

// ---------------- precompute: fold s, rad_w2/rad_b2, proj_w*, 0.25 into
// MT (224x64, transposed: MT[c][k]), cvec(224), b0s(128).
// Blocks >= 65 zero-fill G/Ab and cnt (replaces two hipMemsetAsync).
__global__ __launch_bounds__(256) void precomp_kernel(
    const float* __restrict__ exp_w, const float* __restrict__ exp_b,
    const float* __restrict__ rad_w2, const float* __restrict__ rad_b2,
    const float* __restrict__ proj_w0, const float* __restrict__ proj_b0,
    const float* __restrict__ proj_w1, const float* __restrict__ proj_w2,
    float* __restrict__ MT, float* __restrict__ cvec, float* __restrict__ b0s,
    float* __restrict__ zbase, long long zf4, int* __restrict__ cnt, int Nn)
{
    if (blockIdx.x >= 65) {
        const long long tid = (long long)(blockIdx.x - 65) * 256 + threadIdx.x;
        const long long stride = (long long)ZBLK * 256;
        float4 z = make_float4(0.f, 0.f, 0.f, 0.f);
        for (long long i = tid; i < zf4; i += stride) ((float4*)zbase)[i] = z;
        for (long long i = tid; i < Nn; i += stride) cnt[i] = 0;
        return;
    }
    const int r = blockIdx.x;   // 0..63 -> M row r; 64 -> cvec/b0s
    const int c = threadIdx.x;  // 0..255
    const float* wrow = (r < FCn) ? (rad_w2 + (long long)r * 384) : rad_b2;
    float acc = 0.f;
    if (c < 128) {
        for (int q = 0; q < 128; ++q)
            acc += wrow[q] * (exp_w[q] + exp_b[q]) * proj_w0[q * 128 + c];
    } else if (c < 192) {
        const int d = c - 128;
        for (int q = 0; q < 128; ++q)
            acc += wrow[128 + q] * (exp_w[q] + exp_b[q]) * proj_w1[q * 64 + d];
    } else if (c < 224) {
        const int d = c - 192;
        for (int q = 0; q < 128; ++q)
            acc += wrow[256 + q] * (exp_w[q] + exp_b[q]) * proj_w2[q * 32 + d];
    }
    acc *= 0.25f;  // 1/sqrt(AVG_AGG)
    if (r < FCn) {
        if (c < 224) MT[c * FCn + r] = acc;   // MT[c][k]
    } else {
        cvec[c] = acc;
        if (c < 128) b0s[c] = 0.25f * proj_b0[c];
    }
}

// ---------------- CSR build
__global__ __launch_bounds__(256) void hist_kernel(const int* __restrict__ dst, int* __restrict__ cnt, int E)
{
    for (int e = blockIdx.x * 256 + threadIdx.x; e < E; e += gridDim.x * 256)
        atomicAdd(&cnt[dst[e]], 1);
}

__global__ __launch_bounds__(256) void scan_kernel(const int* __restrict__ cnt, int* __restrict__ off,
                                                   int* __restrict__ cur, int Nn, int Etot)
{
    __shared__ int part[256];
    __shared__ int spart[257];
    const int t = threadIdx.x;
    const int per = (Nn + 255) / 256;
    int s = 0;
    #pragma unroll 8
    for (int i = 0; i < per; ++i) {
        const int idx = t * per + i;
        if (idx < Nn) s += cnt[idx];
    }
    part[t] = s;
    __syncthreads();
    if (t == 0) {
        int run = 0;
        spart[0] = 0;
        for (int i = 0; i < 256; ++i) { run += part[i]; spart[i + 1] = run; }
    }
    __syncthreads();
    int run = spart[t];
    #pragma unroll 8
    for (int i = 0; i < per; ++i) {
        const int idx = t * per + i;
        if (idx < Nn) { off[idx] = run; cur[idx] = run; run += cnt[idx]; }
    }
    if (t == 0) off[Nn] = Etot;
}

__global__ __launch_bounds__(256) void scatter_kernel(const int* __restrict__ dst, int* __restrict__ cur,
                                                      int* __restrict__ eids, int E)
{
    for (int e = blockIdx.x * 256 + threadIdx.x; e < E; e += gridDim.x * 256) {
        const int pos = atomicAdd(&cur[dst[e]], 1);
        eids[pos] = e;
    }
}

// ---------------- pass 1: GEMM1 + in-register LN/silu + segment-accumulate G
// r9: bijective XOR swizzle (r8's row-base shift overlapped rows 31/32);
// Ea stride 9 -> 20 KB LDS -> 8 blocks/CU with bounds (256,8);
// unroll-2 GEMM1 k-loop; 8-edge fast path in the segment loop.
__global__ __launch_bounds__(256, 8) void accumG_kernel(
    const float* __restrict__ edge_attr,    // E x 9
    const float* __restrict__ edge_scalars, // E x 64
    const int*   __restrict__ eids,         // E (sorted pos -> edge id)
    const int*   __restrict__ edge_dst,     // E
    const float* __restrict__ rad_w1,       // 64 x 64
    const float* __restrict__ rad_b1,       // 64
    const float* __restrict__ rad_gamma,    // 64
    const float* __restrict__ rad_beta,     // 64
    float* __restrict__ G,                  // N x 576 (zero-initialized)
    float* __restrict__ Ab,                 // N x 12  (zero-initialized)
    int E)
{
    __shared__ float XT[XSZ];         // X^T [k][e] swizzled; reused as He [e][k]
    __shared__ float Ea[TEB * 9];     // [e][j], linear
    __shared__ int   dst_l[TEB];
    const int t = threadIdx.x;
    const int p0 = blockIdx.x * TEB;

    if (t < TEB) {
        const int p = p0 + t;
        const int eid = (p < E) ? eids[p] : -1;
        dst_l[t] = (eid >= 0) ? edge_dst[eid] : -1;
    }

    // ---- stage X^T (gathered 256B rows), XOR-swizzled writes: 2 lanes/bank
    #pragma unroll
    for (int i = 0; i < 4; ++i) {
        const int idx = i * 256 + t;
        const int e  = idx >> 4;
        const int kq = idx & 15;
        const int p  = p0 + e;
        const int eid = (p < E) ? eids[p] : -1;
        float4 v = make_float4(0.f, 0.f, 0.f, 0.f);
        if (eid >= 0) v = *(const float4*)(edge_scalars + (long long)eid * FCn + kq * 4);
        // rows r = kq*4+j share (r>>3)&7 == (kq>>1)&7 for j=0..3
        const int ec = e ^ (((kq >> 1) & 7) << 2);
        const int b0 = (kq * 4) * 68 + ec;
        XT[b0       ] = v.x;
        XT[b0 + 68  ] = v.y;
        XT[b0 + 136 ] = v.z;
        XT[b0 + 204 ] = v.w;
    }
    // edge_attr: linear LDS copy (reads in e-loop are wave-uniform broadcasts)
    for (int i = t; i < TEB * 9; i += 256) {
        const int e = i / 9, j = i - e * 9;
        const int p = p0 + e;
        const int eid = (p < E) ? eids[p] : -1;
        Ea[i] = (eid >= 0) ? edge_attr[(long long)eid * 9 + j] : 0.f;
    }
    __syncthreads();

    // ---- GEMM1: H = X @ W1 + b1 (64e x 64c), per-thread 4x4, acc in regs
    const int eg = t >> 4, cg = t & 15;
    float a[4][4];
    #pragma unroll
    for (int i = 0; i < 4; ++i)
        #pragma unroll
        for (int j = 0; j < 4; ++j) a[i][j] = 0.f;
    #pragma unroll 2
    for (int k = 0; k < FCn; ++k) {
        const float4 xv = *(const float4*)&XT[xidx(k, eg * 4)];
        const float4 wv = *(const float4*)&rad_w1[k * FCn + cg * 4];
        const float xe[4] = {xv.x, xv.y, xv.z, xv.w};
        const float wc[4] = {wv.x, wv.y, wv.z, wv.w};
        #pragma unroll
        for (int i = 0; i < 4; ++i)
            #pragma unroll
            for (int j = 0; j < 4; ++j)
                a[i][j] += xe[i] * wc[j];
    }
    {
        const float4 bv = *(const float4*)&rad_b1[cg * 4];
        const float bb[4] = {bv.x, bv.y, bv.z, bv.w};
        #pragma unroll
        for (int i = 0; i < 4; ++i)
            #pragma unroll
            for (int j = 0; j < 4; ++j) a[i][j] += bb[j];
    }

    // ---- LN stats: reduce across the 16 cg-lanes (contiguous in wave)
    float s1[4], s2[4];
    #pragma unroll
    for (int i = 0; i < 4; ++i) {
        s1[i] = a[i][0] + a[i][1] + a[i][2] + a[i][3];
        s2[i] = a[i][0]*a[i][0] + a[i][1]*a[i][1] + a[i][2]*a[i][2] + a[i][3]*a[i][3];
    }
    #pragma unroll
    for (int m = 1; m < 16; m <<= 1) {
        #pragma unroll
        for (int i = 0; i < 4; ++i) {
            s1[i] += __shfl_xor(s1[i], m);
            s2[i] += __shfl_xor(s2[i], m);
        }
    }

    __syncthreads();   // all XT (X^T) reads done; safe to overwrite with He

    {
        const float4 gm = *(const float4*)&rad_gamma[cg * 4];
        const float4 bt = *(const float4*)&rad_beta[cg * 4];
        const float gv[4] = {gm.x, gm.y, gm.z, gm.w};
        const float bv2[4] = {bt.x, bt.y, bt.z, bt.w};
        #pragma unroll
        for (int i = 0; i < 4; ++i) {
            const float mu  = s1[i] * (1.f / 64.f);
            const float var = s2[i] * (1.f / 64.f) - mu * mu;
            const float rs  = rsqrtf(var + 1e-5f);
            float o[4];
            #pragma unroll
            for (int j = 0; j < 4; ++j) {
                const float x = (a[i][j] - mu) * rs * gv[j] + bv2[j];
                o[j] = silu_f(x);
            }
            *(float4*)&XT[xidx(eg * 4 + i, cg * 4)] = make_float4(o[0], o[1], o[2], o[3]);
        }
    }
    __syncthreads();

    // ---- segment accumulation of G and A (registers), flush on dst change.
    // dst_l non-decreasing (CSR order) -> wave-uniform 8/4-edge fast paths.
    const int k  = t & 63;
    const int jg = t >> 6;            // 0..3
    const int j0 = jg, j1 = jg + 4;   // jg==0 additionally owns j=8
    const bool has2 = (jg == 0);
    float g0 = 0.f, g1 = 0.f, g2 = 0.f;
    float a0 = 0.f, a1 = 0.f, a2 = 0.f;
    int curn = dst_l[0];
    int e = 0;
    while (e < TEB) {
        const int nid = dst_l[e];
        if (nid != curn) {
            if (curn >= 0) {
                float* gp = G + (long long)curn * GJK;
                atomicAdd(gp + j0 * 64 + k, g0);
                atomicAdd(gp + j1 * 64 + k, g1);
                if (has2) atomicAdd(gp + 8 * 64 + k, g2);
                if (k == 0) {
                    float* ap = Ab + (long long)curn * ABP;
                    atomicAdd(ap + j0, a0);
                    atomicAdd(ap + j1, a1);
                    if (has2) atomicAdd(ap + 8, a2);
                }
            }
            g0 = g1 = g2 = 0.f; a0 = a1 = a2 = 0.f;
            curn = nid;
        }
        if (nid < 0) break;
        if (e + 8 <= TEB && dst_l[e + 7] == nid) {
            #pragma unroll
            for (int u = 0; u < 8; ++u) {
                const int eu = e + u;
                const float h  = XT[xidx(eu, k)];
                const float e0 = Ea[eu * 9 + j0];
                const float e1 = Ea[eu * 9 + j1];
                g0 = fmaf(e0, h, g0); a0 += e0;
                g1 = fmaf(e1, h, g1); a1 += e1;
                if (has2) {
                    const float e2 = Ea[eu * 9 + 8];
                    g2 = fmaf(e2, h, g2); a2 += e2;
                }
            }
            e += 8;
        } else if (e + 4 <= TEB && dst_l[e + 3] == nid) {
            #pragma unroll
            for (int u = 0; u < 4; ++u) {
                const int eu = e + u;
                const float h  = XT[xidx(eu, k)];
                const float e0 = Ea[eu * 9 + j0];
                const float e1 = Ea[eu * 9 + j1];
                g0 = fmaf(e0, h, g0); a0 += e0;
                g1 = fmaf(e1, h, g1); a1 += e1;
                if (has2) {
                    const float e2 = Ea[eu * 9 + 8];
                    g2 = fmaf(e2, h, g2); a2 += e2;
                }
            }
            e += 4;
        } else {
            const float h  = XT[xidx(e, k)];
            const float e0 = Ea[e * 9 + j0];
            const float e1 = Ea[e * 9 + j1];
            g0 = fmaf(e0, h, g0); a0 += e0;
            g1 = fmaf(e1, h, g1); a1 += e1;
            if (has2) {
                const float e2 = Ea[e * 9 + 8];
                g2 = fmaf(e2, h, g2); a2 += e2;
            }
            e += 1;
        }
    }
    if (curn >= 0) {
        float* gp = G + (long long)curn * GJK;
        atomicAdd(gp + j0 * 64 + k, g0);
        atomicAdd(gp + j1 * 64 + k, g1);
        if (has2) atomicAdd(gp + 8 * 64 + k, g2);
        if (k == 0) {
            float* ap = Ab + (long long)curn * ABP;
            atomicAdd(ap + j0, a0);
            atomicAdd(ap + j1, a1);
            if (has2) atomicAdd(ap + 8, a2);
        }
    }
}

// ---------------- pass 2: out[n,c] = G[n,j(c),:]·MT[t(c),:] + Ab[n,j(c)]*cvec[t(c)]
//                                     + (c<128 ? deg*b0s[c] : 0)
// 16 nodes/block (Nn/16 = 1250 exactly) halves the per-block MT register
// reload vs 8. LDS-staged G, 68-float j-stride, 4-node register groups
// under the hard 128-VGPR cap (acc[8] spills — proven r4).
__global__ __launch_bounds__(512) void project_kernel(
    const float* __restrict__ G, const float* __restrict__ Ab,
    const int*   __restrict__ off,
    const float* __restrict__ MT, const float* __restrict__ cvec,
    const float* __restrict__ b0s,
    float* __restrict__ out, int Nn)
{
    __shared__ float Gs[16 * GJS];    // 39168 B, [nb][j][68]
    const int t = threadIdx.x;

    // out col t -> (T col, edge_attr col)
    int tIdx = 0, jIdx = 0;
    if (t < 128)      { tIdx = t; jIdx = 0; }
    else if (t < 320) { const int idx = t - 128; tIdx = 128 + idx / 3; jIdx = 1 + idx % 3; }
    else if (t < 480) { const int idx = t - 320; tIdx = 192 + idx / 5; jIdx = 4 + idx % 5; }

    const int n0b = blockIdx.x * 16;

    // ---- phase 1: stage 16 nodes of G into LDS (coalesced float4 reads)
    for (int i = t; i < 16 * 144; i += 512) {
        const int nb  = i / 144;
        const int rem = i - nb * 144;           // float4 index within node row
        const int n   = n0b + nb;
        float4 v = make_float4(0.f, 0.f, 0.f, 0.f);
        if (n < Nn) v = *(const float4*)(G + (long long)n * GJK + rem * 4);
        *(float4*)(&Gs[nb * GJS + (rem >> 4) * 68 + (rem & 15) * 4]) = v;
    }

    // MT row into registers (64 floats); constants from global (L2-resident)
    float4 m[16];
    {
        const float* mrow = MT + tIdx * FCn;
        #pragma unroll
        for (int q = 0; q < 16; ++q) m[q] = *(const float4*)(mrow + q * 4);
    }
    const float cvv = cvec[tIdx];
    const float bsv = (t < 128) ? b0s[t] : 0.f;
    __syncthreads();

    // ---- phase 2: four sequential 4-node groups
    #pragma unroll 1
    for (int g = 0; g < 4; ++g) {
        const int n0 = n0b + g * 4;
        if (n0 >= Nn) break;

        float acc[4];
        #pragma unroll
        for (int nb = 0; nb < 4; ++nb) {
            const int n = min(n0 + nb, Nn - 1);
            const int deg = off[n + 1] - off[n];
            acc[nb] = Ab[(long long)n * ABP + jIdx] * cvv + (float)deg * bsv;
        }
        const float* gb = &Gs[(g * 4) * GJS + jIdx * 68];
        #pragma unroll
        for (int q = 0; q < 16; ++q) {
            const float4 mq = m[q];
            #pragma unroll
            for (int nb = 0; nb < 4; ++nb) {
                const float4 gv = *(const float4*)(gb + nb * GJS + q * 4);
                acc[nb] += mq.x * gv.x + mq.y * gv.y + mq.z * gv.z + mq.w * gv.w;
            }
        }
        if (t < 480) {
            #pragma unroll
            for (int nb = 0; nb < 4; ++nb)
                if (n0 + nb < Nn)
                    out[(long long)(n0 + nb) * 480 + t] = acc[nb];
        }
    }
}

extern "C" void kernel_launch(void* const* d_in, const int* in_sizes, int n_in,
                              void* d_out, int out_size, void* d_ws, size_t ws_size,
                              hipStream_t stream)
{
    const float* edge_attr    = (const float*)d_in[1];
    const float* edge_scalars = (const float*)d_in[2];
    const int*   edge_dst     = (const int*)d_in[4];
    const float* exp_w     = (const float*)d_in[6];
    const float* exp_b     = (const float*)d_in[7];
    const float* rad_w1    = (const float*)d_in[8];
    const float* rad_b1    = (const float*)d_in[9];
    const float* rad_gamma = (const float*)d_in[10];
    const float* rad_beta  = (const float*)d_in[11];
    const float* rad_w2    = (const float*)d_in[12];
    const float* rad_b2    = (const float*)d_in[13];
    const float* proj_w0   = (const float*)d_in[14];
    const float* proj_b0   = (const float*)d_in[15];
    const float* proj_w1   = (const float*)d_in[16];
    const float* proj_w2   = (const float*)d_in[17];
    float* out = (float*)d_out;
    const int E = in_sizes[4];
    const int Nn = out_size / 480;

    // ws layout: MT, cvec, b0s, off, cnt, cur, eids, G, Ab
    float* MT   = (float*)d_ws;                 // 224*64
    float* cvec = MT + 224 * FCn;               // 256
    float* b0s  = cvec + 256;                   // 128
    int* off  = (int*)(b0s + 128);              // Nn+1
    int* cnt  = off + (Nn + 1);                 // Nn
    int* cur  = cnt + Nn;                       // Nn
    int* eids = cur + Nn;                       // E
    size_t gOff = (size_t)((char*)(eids + E) - (char*)d_ws);
    gOff = (gOff + 255) & ~(size_t)255;
    float* G  = (float*)((char*)d_ws + gOff);   // Nn x 576
    float* Ab = G + (size_t)Nn * GJK;           // Nn x 12 (contiguous with G)

    const long long zf4 = ((long long)Nn * (GJK + ABP)) >> 2;  // G+Ab float4 count
    precomp_kernel<<<65 + ZBLK, 256, 0, stream>>>(exp_w, exp_b, rad_w2, rad_b2,
                                                  proj_w0, proj_b0, proj_w1, proj_w2,
                                                  MT, cvec, b0s, G, zf4, cnt, Nn);
    hist_kernel<<<512, 256, 0, stream>>>(edge_dst, cnt, E);
    scan_kernel<<<1, 256, 0, stream>>>(cnt, off, cur, Nn, E);
    scatter_kernel<<<512, 256, 0, stream>>>(edge_dst, cur, eids, E);

    const int blocks = (E + TEB - 1) / TEB;
    accumG_kernel<<<blocks, 256, 0, stream>>>(edge_attr, edge_scalars, eids, edge_dst,
                                              rad_w1, rad_b1, rad_gamma, rad_beta,
                                              G, Ab, E);
    const int pblocks = (Nn + 15) / 16;
    project_kernel<<<pblocks, 512, 0, stream>>>(G, Ab, off, MT, cvec, b0s, out, Nn);
}

// Round 10
// 462.889 us; speedup vs baseline: 2.0602x; 1.0026x over previous
//
#include <hip/hip_runtime.h>

#define FCn 64      // FC
#define TEB 64      // edges per block (pass 1)
#define GJK 576     // 9*64 floats of G per node
#define GJS 612     // 9*68 padded LDS stride per node (project)
#define ABP 12      // padded A-row stride per node (global Ab)
#define ZBLK 512    // zero-fill blocks appended to precomp grid
#define XSZ (64*68) // XT buffer: 64 rows x 68 stride

__device__ __forceinline__ float silu_f(float x) { return x / (1.f + __expf(-x)); }

// ---------------- precompute: fold s, rad_w2/rad_b2, proj_w*, 0.25 into
// MT (224x64, transposed: MT[c][k]), cvec(224), b0s(128).
// Blocks >= 65 zero-fill G/Ab and cnt (replaces two hipMemsetAsync).
__global__ __launch_bounds__(256) void precomp_kernel(
    const float* __restrict__ exp_w, const float* __restrict__ exp_b,
    const float* __restrict__ rad_w2, const float* __restrict__ rad_b2,
    const float* __restrict__ proj_w0, const float* __restrict__ proj_b0,
    const float* __restrict__ proj_w1, const float* __restrict__ proj_w2,
    float* __restrict__ MT, float* __restrict__ cvec, float* __restrict__ b0s,
    float* __restrict__ zbase, long long zf4, int* __restrict__ cnt, int Nn)
{
    if (blockIdx.x >= 65) {
        const long long tid = (long long)(blockIdx.x - 65) * 256 + threadIdx.x;
        const long long stride = (long long)ZBLK * 256;
        float4 z = make_float4(0.f, 0.f, 0.f, 0.f);
        for (long long i = tid; i < zf4; i += stride) ((float4*)zbase)[i] = z;
        for (long long i = tid; i < Nn; i += stride) cnt[i] = 0;
        return;
    }
    const int r = blockIdx.x;   // 0..63 -> M row r; 64 -> cvec/b0s
    const int c = threadIdx.x;  // 0..255
    const float* wrow = (r < FCn) ? (rad_w2 + (long long)r * 384) : rad_b2;
    float acc = 0.f;
    if (c < 128) {
        for (int q = 0; q < 128; ++q)
            acc += wrow[q] * (exp_w[q] + exp_b[q]) * proj_w0[q * 128 + c];
    } else if (c < 192) {
        const int d = c - 128;
        for (int q = 0; q < 128; ++q)
            acc += wrow[128 + q] * (exp_w[q] + exp_b[q]) * proj_w1[q * 64 + d];
    } else if (c < 224) {
        const int d = c - 192;
        for (int q = 0; q < 128; ++q)
            acc += wrow[256 + q] * (exp_w[q] + exp_b[q]) * proj_w2[q * 32 + d];
    }
    acc *= 0.25f;  // 1/sqrt(AVG_AGG)
    if (r < FCn) {
        if (c < 224) MT[c * FCn + r] = acc;   // MT[c][k]
    } else {
        cvec[c] = acc;
        if (c < 128) b0s[c] = 0.25f * proj_b0[c];
    }
}

// ---------------- CSR build
__global__ __launch_bounds__(256) void hist_kernel(const int* __restrict__ dst, int* __restrict__ cnt, int E)
{
    for (int e = blockIdx.x * 256 + threadIdx.x; e < E; e += gridDim.x * 256)
        atomicAdd(&cnt[dst[e]], 1);
}

__global__ __launch_bounds__(256) void scan_kernel(const int* __restrict__ cnt, int* __restrict__ off,
                                                   int* __restrict__ cur, int Nn, int Etot)
{
    __shared__ int part[256];
    __shared__ int spart[257];
    const int t = threadIdx.x;
    const int per = (Nn + 255) / 256;
    int s = 0;
    #pragma unroll 8
    for (int i = 0; i < per; ++i) {
        const int idx = t * per + i;
        if (idx < Nn) s += cnt[idx];
    }
    part[t] = s;
    __syncthreads();
    if (t == 0) {
        int run = 0;
        spart[0] = 0;
        for (int i = 0; i < 256; ++i) { run += part[i]; spart[i + 1] = run; }
    }
    __syncthreads();
    int run = spart[t];
    #pragma unroll 8
    for (int i = 0; i < per; ++i) {
        const int idx = t * per + i;
        if (idx < Nn) { off[idx] = run; cur[idx] = run; run += cnt[idx]; }
    }
    if (t == 0) off[Nn] = Etot;
}

__global__ __launch_bounds__(256) void scatter_kernel(const int* __restrict__ dst, int* __restrict__ cur,
                                                      int* __restrict__ eids, int E)
{
    for (int e = blockIdx.x * 256 + threadIdx.x; e < E; e += gridDim.x * 256) {
        const int pos = atomicAdd(&cur[dst[e]], 1);
        eids[pos] = e;
    }
}

// ---------------- pass 1: GEMM1 + in-register LN/silu + segment-accumulate G
// r10: swizzle ONLY the X^T staging (the 8-way conflict source). GEMM1
// compensates with a wave-uniform XOR (SALU, ~free). He is stored LINEAR
// [e][k] so the hot segment loop has zero swizzle VALU (r9's xidx in that
// loop cost +18us). Ea stride 9 -> 20 KB LDS -> 8 blocks/CU.
__global__ __launch_bounds__(256, 8) void accumG_kernel(
    const float* __restrict__ edge_attr,    // E x 9
    const float* __restrict__ edge_scalars, // E x 64
    const int*   __restrict__ eids,         // E (sorted pos -> edge id)
    const int*   __restrict__ edge_dst,     // E
    const float* __restrict__ rad_w1,       // 64 x 64
    const float* __restrict__ rad_b1,       // 64
    const float* __restrict__ rad_gamma,    // 64
    const float* __restrict__ rad_beta,     // 64
    float* __restrict__ G,                  // N x 576 (zero-initialized)
    float* __restrict__ Ab,                 // N x 12  (zero-initialized)
    int E)
{
    __shared__ float XT[XSZ];         // X^T [k][e^s(k)] swizzled; reused as He [e][k] linear
    __shared__ float Ea[TEB * 9];     // [e][j], linear
    __shared__ int   dst_l[TEB];
    const int t = threadIdx.x;
    const int p0 = blockIdx.x * TEB;

    if (t < TEB) {
        const int p = p0 + t;
        const int eid = (p < E) ? eids[p] : -1;
        dst_l[t] = (eid >= 0) ? edge_dst[eid] : -1;
    }

    // ---- stage X^T (gathered 256B rows), XOR-swizzled e-index: 2 lanes/bank.
    // Edge e of row r=4kq+j stored at column e ^ (((kq>>1)&7)<<2); XOR value
    // is a multiple of 4 < 64 -> bijective, aligned quads move whole.
    #pragma unroll
    for (int i = 0; i < 4; ++i) {
        const int idx = i * 256 + t;
        const int e  = idx >> 4;
        const int kq = idx & 15;
        const int p  = p0 + e;
        const int eid = (p < E) ? eids[p] : -1;
        float4 v = make_float4(0.f, 0.f, 0.f, 0.f);
        if (eid >= 0) v = *(const float4*)(edge_scalars + (long long)eid * FCn + kq * 4);
        const int ec = e ^ (((kq >> 1) & 7) << 2);
        const int b0 = (kq * 4) * 68 + ec;
        XT[b0       ] = v.x;
        XT[b0 + 68  ] = v.y;
        XT[b0 + 136 ] = v.z;
        XT[b0 + 204 ] = v.w;
    }
    // edge_attr: linear LDS copy (reads in e-loop are wave-uniform broadcasts)
    for (int i = t; i < TEB * 9; i += 256) {
        const int e = i / 9, j = i - e * 9;
        const int p = p0 + e;
        const int eid = (p < E) ? eids[p] : -1;
        Ea[i] = (eid >= 0) ? edge_attr[(long long)eid * 9 + j] : 0.f;
    }
    __syncthreads();

    // ---- GEMM1: H = X @ W1 + b1 (64e x 64c), per-thread 4x4, acc in regs.
    // su = (k>>3)&7 is wave-uniform (SALU); read stays aligned float4 broadcast.
    const int eg = t >> 4, cg = t & 15;
    float a[4][4];
    #pragma unroll
    for (int i = 0; i < 4; ++i)
        #pragma unroll
        for (int j = 0; j < 4; ++j) a[i][j] = 0.f;
    #pragma unroll 2
    for (int k = 0; k < FCn; ++k) {
        const int su = (k >> 3) & 7;
        const float4 xv = *(const float4*)&XT[k * 68 + ((eg ^ su) << 2)];
        const float4 wv = *(const float4*)&rad_w1[k * FCn + cg * 4];
        const float xe[4] = {xv.x, xv.y, xv.z, xv.w};
        const float wc[4] = {wv.x, wv.y, wv.z, wv.w};
        #pragma unroll
        for (int i = 0; i < 4; ++i)
            #pragma unroll
            for (int j = 0; j < 4; ++j)
                a[i][j] += xe[i] * wc[j];
    }
    {
        const float4 bv = *(const float4*)&rad_b1[cg * 4];
        const float bb[4] = {bv.x, bv.y, bv.z, bv.w};
        #pragma unroll
        for (int i = 0; i < 4; ++i)
            #pragma unroll
            for (int j = 0; j < 4; ++j) a[i][j] += bb[j];
    }

    // ---- LN stats: reduce across the 16 cg-lanes (contiguous in wave)
    float s1[4], s2[4];
    #pragma unroll
    for (int i = 0; i < 4; ++i) {
        s1[i] = a[i][0] + a[i][1] + a[i][2] + a[i][3];
        s2[i] = a[i][0]*a[i][0] + a[i][1]*a[i][1] + a[i][2]*a[i][2] + a[i][3]*a[i][3];
    }
    #pragma unroll
    for (int m = 1; m < 16; m <<= 1) {
        #pragma unroll
        for (int i = 0; i < 4; ++i) {
            s1[i] += __shfl_xor(s1[i], m);
            s2[i] += __shfl_xor(s2[i], m);
        }
    }

    __syncthreads();   // all XT (X^T) reads done; safe to overwrite with He

    {
        const float4 gm = *(const float4*)&rad_gamma[cg * 4];
        const float4 bt = *(const float4*)&rad_beta[cg * 4];
        const float gv[4] = {gm.x, gm.y, gm.z, gm.w};
        const float bv2[4] = {bt.x, bt.y, bt.z, bt.w};
        #pragma unroll
        for (int i = 0; i < 4; ++i) {
            const float mu  = s1[i] * (1.f / 64.f);
            const float var = s2[i] * (1.f / 64.f) - mu * mu;
            const float rs  = rsqrtf(var + 1e-5f);
            float o[4];
            #pragma unroll
            for (int j = 0; j < 4; ++j) {
                const float x = (a[i][j] - mu) * rs * gv[j] + bv2[j];
                o[j] = silu_f(x);
            }
            *(float4*)&XT[(eg * 4 + i) * 68 + cg * 4] = make_float4(o[0], o[1], o[2], o[3]);
        }
    }
    __syncthreads();

    // ---- segment accumulation of G and A (registers), flush on dst change.
    // He reads are LINEAR (k = lane&63 -> stride-1, conflict-free, no swizzle
    // VALU). dst_l non-decreasing -> wave-uniform 8/4-edge fast paths.
    const int k  = t & 63;
    const int jg = t >> 6;            // 0..3
    const int j0 = jg, j1 = jg + 4;   // jg==0 additionally owns j=8
    const bool has2 = (jg == 0);
    float g0 = 0.f, g1 = 0.f, g2 = 0.f;
    float a0 = 0.f, a1 = 0.f, a2 = 0.f;
    int curn = dst_l[0];
    int e = 0;
    while (e < TEB) {
        const int nid = dst_l[e];
        if (nid != curn) {
            if (curn >= 0) {
                float* gp = G + (long long)curn * GJK;
                atomicAdd(gp + j0 * 64 + k, g0);
                atomicAdd(gp + j1 * 64 + k, g1);
                if (has2) atomicAdd(gp + 8 * 64 + k, g2);
                if (k == 0) {
                    float* ap = Ab + (long long)curn * ABP;
                    atomicAdd(ap + j0, a0);
                    atomicAdd(ap + j1, a1);
                    if (has2) atomicAdd(ap + 8, a2);
                }
            }
            g0 = g1 = g2 = 0.f; a0 = a1 = a2 = 0.f;
            curn = nid;
        }
        if (nid < 0) break;
        if (e + 8 <= TEB && dst_l[e + 7] == nid) {
            #pragma unroll
            for (int u = 0; u < 8; ++u) {
                const int eu = e + u;
                const float h  = XT[eu * 68 + k];
                const float e0 = Ea[eu * 9 + j0];
                const float e1 = Ea[eu * 9 + j1];
                g0 = fmaf(e0, h, g0); a0 += e0;
                g1 = fmaf(e1, h, g1); a1 += e1;
                if (has2) {
                    const float e2 = Ea[eu * 9 + 8];
                    g2 = fmaf(e2, h, g2); a2 += e2;
                }
            }
            e += 8;
        } else if (e + 4 <= TEB && dst_l[e + 3] == nid) {
            #pragma unroll
            for (int u = 0; u < 4; ++u) {
                const int eu = e + u;
                const float h  = XT[eu * 68 + k];
                const float e0 = Ea[eu * 9 + j0];
                const float e1 = Ea[eu * 9 + j1];
                g0 = fmaf(e0, h, g0); a0 += e0;
                g1 = fmaf(e1, h, g1); a1 += e1;
                if (has2) {
                    const float e2 = Ea[eu * 9 + 8];
                    g2 = fmaf(e2, h, g2); a2 += e2;
                }
            }
            e += 4;
        } else {
            const float h  = XT[e * 68 + k];
            const float e0 = Ea[e * 9 + j0];
            const float e1 = Ea[e * 9 + j1];
            g0 = fmaf(e0, h, g0); a0 += e0;
            g1 = fmaf(e1, h, g1); a1 += e1;
            if (has2) {
                const float e2 = Ea[e * 9 + 8];
                g2 = fmaf(e2, h, g2); a2 += e2;
            }
            e += 1;
        }
    }
    if (curn >= 0) {
        float* gp = G + (long long)curn * GJK;
        atomicAdd(gp + j0 * 64 + k, g0);
        atomicAdd(gp + j1 * 64 + k, g1);
        if (has2) atomicAdd(gp + 8 * 64 + k, g2);
        if (k == 0) {
            float* ap = Ab + (long long)curn * ABP;
            atomicAdd(ap + j0, a0);
            atomicAdd(ap + j1, a1);
            if (has2) atomicAdd(ap + 8, a2);
        }
    }
}

// ---------------- pass 2: out[n,c] = G[n,j(c),:]·MT[t(c),:] + Ab[n,j(c)]*cvec[t(c)]
//                                     + (c<128 ? deg*b0s[c] : 0)
// 16 nodes/block (Nn/16 = 1250 exactly). LDS-staged G, 68-float j-stride,
// 4-node register groups under the hard 128-VGPR cap (acc[8] spills — r4).
__global__ __launch_bounds__(512) void project_kernel(
    const float* __restrict__ G, const float* __restrict__ Ab,
    const int*   __restrict__ off,
    const float* __restrict__ MT, const float* __restrict__ cvec,
    const float* __restrict__ b0s,
    float* __restrict__ out, int Nn)
{
    __shared__ float Gs[16 * GJS];    // 39168 B, [nb][j][68]
    const int t = threadIdx.x;

    // out col t -> (T col, edge_attr col)
    int tIdx = 0, jIdx = 0;
    if (t < 128)      { tIdx = t; jIdx = 0; }
    else if (t < 320) { const int idx = t - 128; tIdx = 128 + idx / 3; jIdx = 1 + idx % 3; }
    else if (t < 480) { const int idx = t - 320; tIdx = 192 + idx / 5; jIdx = 4 + idx % 5; }

    const int n0b = blockIdx.x * 16;

    // ---- phase 1: stage 16 nodes of G into LDS (coalesced float4 reads)
    for (int i = t; i < 16 * 144; i += 512) {
        const int nb  = i / 144;
        const int rem = i - nb * 144;           // float4 index within node row
        const int n   = n0b + nb;
        float4 v = make_float4(0.f, 0.f, 0.f, 0.f);
        if (n < Nn) v = *(const float4*)(G + (long long)n * GJK + rem * 4);
        *(float4*)(&Gs[nb * GJS + (rem >> 4) * 68 + (rem & 15) * 4]) = v;
    }

    // MT row into registers (64 floats); constants from global (L2-resident)
    float4 m[16];
    {
        const float* mrow = MT + tIdx * FCn;
        #pragma unroll
        for (int q = 0; q < 16; ++q) m[q] = *(const float4*)(mrow + q * 4);
    }
    const float cvv = cvec[tIdx];
    const float bsv = (t < 128) ? b0s[t] : 0.f;
    __syncthreads();

    // ---- phase 2: four sequential 4-node groups
    #pragma unroll 1
    for (int g = 0; g < 4; ++g) {
        const int n0 = n0b + g * 4;
        if (n0 >= Nn) break;

        float acc[4];
        #pragma unroll
        for (int nb = 0; nb < 4; ++nb) {
            const int n = min(n0 + nb, Nn - 1);
            const int deg = off[n + 1] - off[n];
            acc[nb] = Ab[(long long)n * ABP + jIdx] * cvv + (float)deg * bsv;
        }
        const float* gb = &Gs[(g * 4) * GJS + jIdx * 68];
        #pragma unroll
        for (int q = 0; q < 16; ++q) {
            const float4 mq = m[q];
            #pragma unroll
            for (int nb = 0; nb < 4; ++nb) {
                const float4 gv = *(const float4*)(gb + nb * GJS + q * 4);
                acc[nb] += mq.x * gv.x + mq.y * gv.y + mq.z * gv.z + mq.w * gv.w;
            }
        }
        if (t < 480) {
            #pragma unroll
            for (int nb = 0; nb < 4; ++nb)
                if (n0 + nb < Nn)
                    out[(long long)(n0 + nb) * 480 + t] = acc[nb];
        }
    }
}

extern "C" void kernel_launch(void* const* d_in, const int* in_sizes, int n_in,
                              void* d_out, int out_size, void* d_ws, size_t ws_size,
                              hipStream_t stream)
{
    const float* edge_attr    = (const float*)d_in[1];
    const float* edge_scalars = (const float*)d_in[2];
    const int*   edge_dst     = (const int*)d_in[4];
    const float* exp_w     = (const float*)d_in[6];
    const float* exp_b     = (const float*)d_in[7];
    const float* rad_w1    = (const float*)d_in[8];
    const float* rad_b1    = (const float*)d_in[9];
    const float* rad_gamma = (const float*)d_in[10];
    const float* rad_beta  = (const float*)d_in[11];
    const float* rad_w2    = (const float*)d_in[12];
    const float* rad_b2    = (const float*)d_in[13];
    const float* proj_w0   = (const float*)d_in[14];
    const float* proj_b0   = (const float*)d_in[15];
    const float* proj_w1   = (const float*)d_in[16];
    const float* proj_w2   = (const float*)d_in[17];
    float* out = (float*)d_out;
    const int E = in_sizes[4];
    const int Nn = out_size / 480;

    // ws layout: MT, cvec, b0s, off, cnt, cur, eids, G, Ab
    float* MT   = (float*)d_ws;                 // 224*64
    float* cvec = MT + 224 * FCn;               // 256
    float* b0s  = cvec + 256;                   // 128
    int* off  = (int*)(b0s + 128);              // Nn+1
    int* cnt  = off + (Nn + 1);                 // Nn
    int* cur  = cnt + Nn;                       // Nn
    int* eids = cur + Nn;                       // E
    size_t gOff = (size_t)((char*)(eids + E) - (char*)d_ws);
    gOff = (gOff + 255) & ~(size_t)255;
    float* G  = (float*)((char*)d_ws + gOff);   // Nn x 576
    float* Ab = G + (size_t)Nn * GJK;           // Nn x 12 (contiguous with G)

    const long long zf4 = ((long long)Nn * (GJK + ABP)) >> 2;  // G+Ab float4 count
    precomp_kernel<<<65 + ZBLK, 256, 0, stream>>>(exp_w, exp_b, rad_w2, rad_b2,
                                                  proj_w0, proj_b0, proj_w1, proj_w2,
                                                  MT, cvec, b0s, G, zf4, cnt, Nn);
    hist_kernel<<<512, 256, 0, stream>>>(edge_dst, cnt, E);
    scan_kernel<<<1, 256, 0, stream>>>(cnt, off, cur, Nn, E);
    scatter_kernel<<<512, 256, 0, stream>>>(edge_dst, cur, eids, E);

    const int blocks = (E + TEB - 1) / TEB;
    accumG_kernel<<<blocks, 256, 0, stream>>>(edge_attr, edge_scalars, eids, edge_dst,
                                              rad_w1, rad_b1, rad_gamma, rad_beta,
                                              G, Ab, E);
    const int pblocks = (Nn + 15) / 16;
    project_kernel<<<pblocks, 512, 0, stream>>>(G, Ab, off, MT, cvec, b0s, out, Nn);
}

// Round 11
// 448.514 us; speedup vs baseline: 2.1263x; 1.0321x over previous
//
#include <hip/hip_runtime.h>

#define FCn 64      // FC
#define LDP 68      // padded LDS row stride (floats)
#define TEB 64      // edges per block (pass 1)
#define GJK 576     // 9*64 floats of G per node
#define GJS 612     // 9*68 padded LDS stride per node (project)
#define ABP 12      // padded A-row stride per node
#define ZBLK 512    // zero-fill blocks appended to precomp grid

__device__ __forceinline__ float silu_f(float x) { return x / (1.f + __expf(-x)); }

// ---------------- precompute: fold s, rad_w2/rad_b2, proj_w*, 0.25 into
// MT (224x64, transposed: MT[c][k]), cvec(224), b0s(128).
// Blocks >= 65 zero-fill G/Ab and cnt (replaces two hipMemsetAsync).
__global__ __launch_bounds__(256) void precomp_kernel(
    const float* __restrict__ exp_w, const float* __restrict__ exp_b,
    const float* __restrict__ rad_w2, const float* __restrict__ rad_b2,
    const float* __restrict__ proj_w0, const float* __restrict__ proj_b0,
    const float* __restrict__ proj_w1, const float* __restrict__ proj_w2,
    float* __restrict__ MT, float* __restrict__ cvec, float* __restrict__ b0s,
    float* __restrict__ zbase, long long zf4, int* __restrict__ cnt, int Nn)
{
    if (blockIdx.x >= 65) {
        const long long tid = (long long)(blockIdx.x - 65) * 256 + threadIdx.x;
        const long long stride = (long long)ZBLK * 256;
        float4 z = make_float4(0.f, 0.f, 0.f, 0.f);
        for (long long i = tid; i < zf4; i += stride) ((float4*)zbase)[i] = z;
        for (long long i = tid; i < Nn; i += stride) cnt[i] = 0;
        return;
    }
    const int r = blockIdx.x;   // 0..63 -> M row r; 64 -> cvec/b0s
    const int c = threadIdx.x;  // 0..255
    const float* wrow = (r < FCn) ? (rad_w2 + (long long)r * 384) : rad_b2;
    float acc = 0.f;
    if (c < 128) {
        for (int q = 0; q < 128; ++q)
            acc += wrow[q] * (exp_w[q] + exp_b[q]) * proj_w0[q * 128 + c];
    } else if (c < 192) {
        const int d = c - 128;
        for (int q = 0; q < 128; ++q)
            acc += wrow[128 + q] * (exp_w[q] + exp_b[q]) * proj_w1[q * 64 + d];
    } else if (c < 224) {
        const int d = c - 192;
        for (int q = 0; q < 128; ++q)
            acc += wrow[256 + q] * (exp_w[q] + exp_b[q]) * proj_w2[q * 32 + d];
    }
    acc *= 0.25f;  // 1/sqrt(AVG_AGG)
    if (r < FCn) {
        if (c < 224) MT[c * FCn + r] = acc;   // MT[c][k]
    } else {
        cvec[c] = acc;
        if (c < 128) b0s[c] = 0.25f * proj_b0[c];
    }
}

// ---------------- CSR build
__global__ __launch_bounds__(256) void hist_kernel(const int* __restrict__ dst, int* __restrict__ cnt, int E)
{
    for (int e = blockIdx.x * 256 + threadIdx.x; e < E; e += gridDim.x * 256)
        atomicAdd(&cnt[dst[e]], 1);
}

__global__ __launch_bounds__(256) void scan_kernel(const int* __restrict__ cnt, int* __restrict__ off,
                                                   int* __restrict__ cur, int Nn, int Etot)
{
    __shared__ int part[256];
    __shared__ int spart[257];
    const int t = threadIdx.x;
    const int per = (Nn + 255) / 256;
    int s = 0;
    #pragma unroll 8
    for (int i = 0; i < per; ++i) {
        const int idx = t * per + i;
        if (idx < Nn) s += cnt[idx];
    }
    part[t] = s;
    __syncthreads();
    if (t == 0) {
        int run = 0;
        spart[0] = 0;
        for (int i = 0; i < 256; ++i) { run += part[i]; spart[i + 1] = run; }
    }
    __syncthreads();
    int run = spart[t];
    #pragma unroll 8
    for (int i = 0; i < per; ++i) {
        const int idx = t * per + i;
        if (idx < Nn) { off[idx] = run; cur[idx] = run; run += cnt[idx]; }
    }
    if (t == 0) off[Nn] = Etot;
}

__global__ __launch_bounds__(256) void scatter_kernel(const int* __restrict__ dst, int* __restrict__ cur,
                                                      int* __restrict__ eids, int E)
{
    for (int e = blockIdx.x * 256 + threadIdx.x; e < E; e += gridDim.x * 256) {
        const int pos = atomicAdd(&cur[dst[e]], 1);
        eids[pos] = e;
    }
}

// ---------------- pass 1: GEMM1 + in-register LN/silu + segment-accumulate G
// Reverted to the round-7 configuration (measured 135 us over 5 dispatches).
// The r8 bundle (bounds (256,8) -> VGPR 36->28, Ea stride 9, unroll-2, 8-edge
// path) regressed to 150-152 us DESPITE occupancy 66->72% and conflicts
// 4.6M->0.6M: the tighter VGPR budget cut per-wave ILP in this latency-bound
// loop. Occupancy-vs-ILP: ILP wins here. Swizzles were time-neutral (r9=r10).
__global__ __launch_bounds__(256, 7) void accumG_kernel(
    const float* __restrict__ edge_attr,    // E x 9
    const float* __restrict__ edge_scalars, // E x 64
    const int*   __restrict__ eids,         // E (sorted pos -> edge id)
    const int*   __restrict__ edge_dst,     // E
    const float* __restrict__ rad_w1,       // 64 x 64
    const float* __restrict__ rad_b1,       // 64
    const float* __restrict__ rad_gamma,    // 64
    const float* __restrict__ rad_beta,     // 64
    float* __restrict__ G,                  // N x 576 (zero-initialized)
    float* __restrict__ Ab,                 // N x 12  (zero-initialized)
    int E)
{
    __shared__ float XT[FCn * LDP];   // X^T [k][e]; reused as He [e][k] after LN
    __shared__ float Ea[TEB * ABP];   // [e][j]
    __shared__ int   dst_l[TEB];
    const int t = threadIdx.x;
    const int p0 = blockIdx.x * TEB;

    if (t < TEB) {
        const int p = p0 + t;
        const int eid = (p < E) ? eids[p] : -1;
        dst_l[t] = (eid >= 0) ? edge_dst[eid] : -1;
    }

    // ---- stage X^T (gathered 256B rows) + edge_attr (eids read via L1 broadcast)
    #pragma unroll
    for (int i = 0; i < 4; ++i) {
        const int idx = i * 256 + t;
        const int e  = idx >> 4;
        const int kq = idx & 15;
        const int p  = p0 + e;
        const int eid = (p < E) ? eids[p] : -1;
        float4 v = make_float4(0.f, 0.f, 0.f, 0.f);
        if (eid >= 0) v = *(const float4*)(edge_scalars + (long long)eid * FCn + kq * 4);
        XT[(kq * 4 + 0) * LDP + e] = v.x;
        XT[(kq * 4 + 1) * LDP + e] = v.y;
        XT[(kq * 4 + 2) * LDP + e] = v.z;
        XT[(kq * 4 + 3) * LDP + e] = v.w;
    }
    for (int i = t; i < TEB * 9; i += 256) {
        const int e = i / 9, j = i - e * 9;
        const int p = p0 + e;
        const int eid = (p < E) ? eids[p] : -1;
        Ea[e * ABP + j] = (eid >= 0) ? edge_attr[(long long)eid * 9 + j] : 0.f;
    }
    __syncthreads();

    // ---- GEMM1: H = X @ W1 + b1 (64e x 64c), per-thread 4x4, acc in regs
    const int eg = t >> 4, cg = t & 15;
    float a[4][4];
    #pragma unroll
    for (int i = 0; i < 4; ++i)
        #pragma unroll
        for (int j = 0; j < 4; ++j) a[i][j] = 0.f;
    for (int k = 0; k < FCn; ++k) {
        const float4 xv = *(const float4*)&XT[k * LDP + eg * 4];
        const float4 wv = *(const float4*)&rad_w1[k * FCn + cg * 4];
        const float xe[4] = {xv.x, xv.y, xv.z, xv.w};
        const float wc[4] = {wv.x, wv.y, wv.z, wv.w};
        #pragma unroll
        for (int i = 0; i < 4; ++i)
            #pragma unroll
            for (int j = 0; j < 4; ++j)
                a[i][j] += xe[i] * wc[j];
    }
    {
        const float4 bv = *(const float4*)&rad_b1[cg * 4];
        const float bb[4] = {bv.x, bv.y, bv.z, bv.w};
        #pragma unroll
        for (int i = 0; i < 4; ++i)
            #pragma unroll
            for (int j = 0; j < 4; ++j) a[i][j] += bb[j];
    }

    // ---- LN stats: reduce across the 16 cg-lanes (contiguous in wave)
    float s1[4], s2[4];
    #pragma unroll
    for (int i = 0; i < 4; ++i) {
        s1[i] = a[i][0] + a[i][1] + a[i][2] + a[i][3];
        s2[i] = a[i][0]*a[i][0] + a[i][1]*a[i][1] + a[i][2]*a[i][2] + a[i][3]*a[i][3];
    }
    #pragma unroll
    for (int m = 1; m < 16; m <<= 1) {
        #pragma unroll
        for (int i = 0; i < 4; ++i) {
            s1[i] += __shfl_xor(s1[i], m);
            s2[i] += __shfl_xor(s2[i], m);
        }
    }

    __syncthreads();   // all XT (X^T) reads done; safe to overwrite with He

    {
        const float4 gm = *(const float4*)&rad_gamma[cg * 4];
        const float4 bt = *(const float4*)&rad_beta[cg * 4];
        const float gv[4] = {gm.x, gm.y, gm.z, gm.w};
        const float bv2[4] = {bt.x, bt.y, bt.z, bt.w};
        #pragma unroll
        for (int i = 0; i < 4; ++i) {
            const float mu  = s1[i] * (1.f / 64.f);
            const float var = s2[i] * (1.f / 64.f) - mu * mu;
            const float rs  = rsqrtf(var + 1e-5f);
            float o[4];
            #pragma unroll
            for (int j = 0; j < 4; ++j) {
                const float x = (a[i][j] - mu) * rs * gv[j] + bv2[j];
                o[j] = silu_f(x);
            }
            *(float4*)&XT[(eg * 4 + i) * LDP + cg * 4] = make_float4(o[0], o[1], o[2], o[3]);
        }
    }
    __syncthreads();

    // ---- segment accumulation of G and A (registers), flush on dst change.
    // dst_l is non-decreasing (CSR order) -> wave-uniform 4-edge fast path.
    const int k  = t & 63;
    const int jg = t >> 6;            // 0..3
    const int j0 = jg, j1 = jg + 4;   // jg==0 additionally owns j=8
    const bool has2 = (jg == 0);
    float g0 = 0.f, g1 = 0.f, g2 = 0.f;
    float a0 = 0.f, a1 = 0.f, a2 = 0.f;
    int curn = dst_l[0];
    int e = 0;
    while (e < TEB) {
        const int nid = dst_l[e];
        if (nid != curn) {
            if (curn >= 0) {
                float* gp = G + (long long)curn * GJK;
                atomicAdd(gp + j0 * 64 + k, g0);
                atomicAdd(gp + j1 * 64 + k, g1);
                if (has2) atomicAdd(gp + 8 * 64 + k, g2);
                if (k == 0) {
                    float* ap = Ab + (long long)curn * ABP;
                    atomicAdd(ap + j0, a0);
                    atomicAdd(ap + j1, a1);
                    if (has2) atomicAdd(ap + 8, a2);
                }
            }
            g0 = g1 = g2 = 0.f; a0 = a1 = a2 = 0.f;
            curn = nid;
        }
        if (nid < 0) break;
        if (e + 4 <= TEB && dst_l[e + 3] == nid) {
            #pragma unroll
            for (int u = 0; u < 4; ++u) {
                const int eu = e + u;
                const float h  = XT[eu * LDP + k];
                const float e0 = Ea[eu * ABP + j0];
                const float e1 = Ea[eu * ABP + j1];
                g0 = fmaf(e0, h, g0); a0 += e0;
                g1 = fmaf(e1, h, g1); a1 += e1;
                if (has2) {
                    const float e2 = Ea[eu * ABP + 8];
                    g2 = fmaf(e2, h, g2); a2 += e2;
                }
            }
            e += 4;
        } else {
            const float h  = XT[e * LDP + k];
            const float e0 = Ea[e * ABP + j0];
            const float e1 = Ea[e * ABP + j1];
            g0 = fmaf(e0, h, g0); a0 += e0;
            g1 = fmaf(e1, h, g1); a1 += e1;
            if (has2) {
                const float e2 = Ea[e * ABP + 8];
                g2 = fmaf(e2, h, g2); a2 += e2;
            }
            e += 1;
        }
    }
    if (curn >= 0) {
        float* gp = G + (long long)curn * GJK;
        atomicAdd(gp + j0 * 64 + k, g0);
        atomicAdd(gp + j1 * 64 + k, g1);
        if (has2) atomicAdd(gp + 8 * 64 + k, g2);
        if (k == 0) {
            float* ap = Ab + (long long)curn * ABP;
            atomicAdd(ap + j0, a0);
            atomicAdd(ap + j1, a1);
            if (has2) atomicAdd(ap + 8, a2);
        }
    }
}

// ---------------- pass 2: out[n,c] = G[n,j(c),:]·MT[t(c),:] + Ab[n,j(c)]*cvec[t(c)]
//                                     + (c<128 ? deg*b0s[c] : 0)
// 16 nodes/block (Nn/16 = 1250 exactly). LDS-staged G, 68-float j-stride,
// 4-node register groups under the hard 128-VGPR cap (acc[8] spills — r4).
__global__ __launch_bounds__(512) void project_kernel(
    const float* __restrict__ G, const float* __restrict__ Ab,
    const int*   __restrict__ off,
    const float* __restrict__ MT, const float* __restrict__ cvec,
    const float* __restrict__ b0s,
    float* __restrict__ out, int Nn)
{
    __shared__ float Gs[16 * GJS];    // 39168 B, [nb][j][68]
    const int t = threadIdx.x;

    // out col t -> (T col, edge_attr col)
    int tIdx = 0, jIdx = 0;
    if (t < 128)      { tIdx = t; jIdx = 0; }
    else if (t < 320) { const int idx = t - 128; tIdx = 128 + idx / 3; jIdx = 1 + idx % 3; }
    else if (t < 480) { const int idx = t - 320; tIdx = 192 + idx / 5; jIdx = 4 + idx % 5; }

    const int n0b = blockIdx.x * 16;

    // ---- phase 1: stage 16 nodes of G into LDS (coalesced float4 reads)
    for (int i = t; i < 16 * 144; i += 512) {
        const int nb  = i / 144;
        const int rem = i - nb * 144;           // float4 index within node row
        const int n   = n0b + nb;
        float4 v = make_float4(0.f, 0.f, 0.f, 0.f);
        if (n < Nn) v = *(const float4*)(G + (long long)n * GJK + rem * 4);
        *(float4*)(&Gs[nb * GJS + (rem >> 4) * 68 + (rem & 15) * 4]) = v;
    }

    // MT row into registers (64 floats); constants from global (L2-resident)
    float4 m[16];
    {
        const float* mrow = MT + tIdx * FCn;
        #pragma unroll
        for (int q = 0; q < 16; ++q) m[q] = *(const float4*)(mrow + q * 4);
    }
    const float cvv = cvec[tIdx];
    const float bsv = (t < 128) ? b0s[t] : 0.f;
    __syncthreads();

    // ---- phase 2: four sequential 4-node groups
    #pragma unroll 1
    for (int g = 0; g < 4; ++g) {
        const int n0 = n0b + g * 4;
        if (n0 >= Nn) break;

        float acc[4];
        #pragma unroll
        for (int nb = 0; nb < 4; ++nb) {
            const int n = min(n0 + nb, Nn - 1);
            const int deg = off[n + 1] - off[n];
            acc[nb] = Ab[(long long)n * ABP + jIdx] * cvv + (float)deg * bsv;
        }
        const float* gb = &Gs[(g * 4) * GJS + jIdx * 68];
        #pragma unroll
        for (int q = 0; q < 16; ++q) {
            const float4 mq = m[q];
            #pragma unroll
            for (int nb = 0; nb < 4; ++nb) {
                const float4 gv = *(const float4*)(gb + nb * GJS + q * 4);
                acc[nb] += mq.x * gv.x + mq.y * gv.y + mq.z * gv.z + mq.w * gv.w;
            }
        }
        if (t < 480) {
            #pragma unroll
            for (int nb = 0; nb < 4; ++nb)
                if (n0 + nb < Nn)
                    out[(long long)(n0 + nb) * 480 + t] = acc[nb];
        }
    }
}

extern "C" void kernel_launch(void* const* d_in, const int* in_sizes, int n_in,
                              void* d_out, int out_size, void* d_ws, size_t ws_size,
                              hipStream_t stream)
{
    const float* edge_attr    = (const float*)d_in[1];
    const float* edge_scalars = (const float*)d_in[2];
    const int*   edge_dst     = (const int*)d_in[4];
    const float* exp_w     = (const float*)d_in[6];
    const float* exp_b     = (const float*)d_in[7];
    const float* rad_w1    = (const float*)d_in[8];
    const float* rad_b1    = (const float*)d_in[9];
    const float* rad_gamma = (const float*)d_in[10];
    const float* rad_beta  = (const float*)d_in[11];
    const float* rad_w2    = (const float*)d_in[12];
    const float* rad_b2    = (const float*)d_in[13];
    const float* proj_w0   = (const float*)d_in[14];
    const float* proj_b0   = (const float*)d_in[15];
    const float* proj_w1   = (const float*)d_in[16];
    const float* proj_w2   = (const float*)d_in[17];
    float* out = (float*)d_out;
    const int E = in_sizes[4];
    const int Nn = out_size / 480;

    // ws layout: MT, cvec, b0s, off, cnt, cur, eids, G, Ab
    float* MT   = (float*)d_ws;                 // 224*64
    float* cvec = MT + 224 * FCn;               // 256
    float* b0s  = cvec + 256;                   // 128
    int* off  = (int*)(b0s + 128);              // Nn+1
    int* cnt  = off + (Nn + 1);                 // Nn
    int* cur  = cnt + Nn;                       // Nn
    int* eids = cur + Nn;                       // E
    size_t gOff = (size_t)((char*)(eids + E) - (char*)d_ws);
    gOff = (gOff + 255) & ~(size_t)255;
    float* G  = (float*)((char*)d_ws + gOff);   // Nn x 576
    float* Ab = G + (size_t)Nn * GJK;           // Nn x 12 (contiguous with G)

    const long long zf4 = ((long long)Nn * (GJK + ABP)) >> 2;  // G+Ab float4 count
    precomp_kernel<<<65 + ZBLK, 256, 0, stream>>>(exp_w, exp_b, rad_w2, rad_b2,
                                                  proj_w0, proj_b0, proj_w1, proj_w2,
                                                  MT, cvec, b0s, G, zf4, cnt, Nn);
    hist_kernel<<<512, 256, 0, stream>>>(edge_dst, cnt, E);
    scan_kernel<<<1, 256, 0, stream>>>(cnt, off, cur, Nn, E);
    scatter_kernel<<<512, 256, 0, stream>>>(edge_dst, cur, eids, E);

    const int blocks = (E + TEB - 1) / TEB;
    accumG_kernel<<<blocks, 256, 0, stream>>>(edge_attr, edge_scalars, eids, edge_dst,
                                              rad_w1, rad_b1, rad_gamma, rad_beta,
                                              G, Ab, E);
    const int pblocks = (Nn + 15) / 16;
    project_kernel<<<pblocks, 512, 0, stream>>>(G, Ab, off, MT, cvec, b0s, out, Nn);
}